// Round 4
// baseline (634.689 us; speedup 1.0000x reference)
//
#include <hip/hip_runtime.h>

#define B_ 16
#define D_ 768
#define N_ 4096
#define Q_ 128

typedef __attribute__((ext_vector_type(4))) float f32x4;
typedef __attribute__((ext_vector_type(8))) short short8;
typedef __attribute__((ext_vector_type(4))) short sv4;

__device__ __forceinline__ unsigned short f2bf(float f) {
  union { float f; unsigned u; } x; x.f = f;
  unsigned u = x.u;
  unsigned r = u + 0x7fffu + ((u >> 16) & 1u);
  return (unsigned short)(r >> 16);
}

// ---------------- prep: z=0 cast Wv; z=1 transpose Wq; z=2 transpose Wk; ----------------
// z=3: vec-mat folds (by=0: wkbq=Wk^T bq; by=1: bias2=bk^T Wq; by=2,bx=0: bqbk)
__global__ __launch_bounds__(256) void prep_kernel(
    const float* __restrict__ Wv, const float* __restrict__ Wq,
    const float* __restrict__ Wk, const float* __restrict__ bq,
    const float* __restrict__ bk,
    unsigned short* __restrict__ Wvb, unsigned short* __restrict__ WqTb,
    unsigned short* __restrict__ WkTb,
    float* __restrict__ wkbq, float* __restrict__ bias2, float* __restrict__ bqbk) {
  __shared__ float tile[32][33];
  const int z = blockIdx.z;
  const int t = threadIdx.x;
  if (z == 0) {
    int i = (blockIdx.y * 24 + blockIdx.x) * 256 + t;  // 576*256 = 768*768/4
    float4 v = ((const float4*)Wv)[i];
    ushort4 o;
    o.x = f2bf(v.x); o.y = f2bf(v.y); o.z = f2bf(v.z); o.w = f2bf(v.w);
    ((ushort4*)Wvb)[i] = o;
  } else if (z <= 2) {
    const float* src = (z == 1) ? Wq : Wk;
    unsigned short* dst = (z == 1) ? WqTb : WkTb;
    int bx = blockIdx.x * 32, by = blockIdx.y * 32;
    int tx = t & 31, ty = t >> 5;
    #pragma unroll
    for (int i = 0; i < 32; i += 8)
      tile[ty + i][tx] = src[(size_t)(by + ty + i) * D_ + bx + tx];
    __syncthreads();
    #pragma unroll
    for (int i = 0; i < 32; i += 8)
      dst[(size_t)(bx + ty + i) * D_ + by + tx] = f2bf(tile[tx][ty + i]);
  } else {
    const int bx = blockIdx.x, by = blockIdx.y;
    if (by < 2) {
      if (bx >= 3) return;
      const float* M = by ? Wq : Wk;
      const float* vec = by ? bk : bq;
      float* outp = by ? bias2 : wkbq;
      const int col = bx * 256 + t;
      float s = 0.f;
      #pragma unroll 4
      for (int n = 0; n < D_; n++) s += M[(size_t)n * D_ + col] * vec[n];
      outp[col] = s;
    } else if (by == 2 && bx == 0) {
      float s = 0.f;
      for (int k = t; k < D_; k += 256) s += bq[k] * bk[k];
      #pragma unroll
      for (int off = 32; off; off >>= 1) s += __shfl_xor(s, off);
      __shared__ float red[4];
      if ((t & 63) == 0) red[t >> 6] = s;
      __syncthreads();
      if (t == 0) bqbk[0] = red[0] + red[1] + red[2] + red[3];
    }
  }
}

// ---------------- text prep: cast fp32->bf16, row entropy, skq row-dot ------------------
__global__ __launch_bounds__(256) void text_prep_kernel(
    const float* __restrict__ text, unsigned short* __restrict__ textb,
    float* __restrict__ ent_t, const float* __restrict__ wkbq,
    const float* __restrict__ bqbk, float* __restrict__ skq) {
  int row = blockIdx.x * 4 + (threadIdx.x >> 6);
  int lane = threadIdx.x & 63;
  const float4* src = (const float4*)(text + (size_t)row * D_);
  const float4* w4p = (const float4*)wkbq;
  ushort4* dst = (ushort4*)(textb + (size_t)row * D_);
  float s = 0.f, tt = 0.f, s2 = 0.f;
  #pragma unroll
  for (int j = 0; j < 3; j++) {
    float4 v = src[lane + 64 * j];
    float4 w = w4p[lane + 64 * j];
    float e0 = __expf(v.x), e1 = __expf(v.y), e2 = __expf(v.z), e3 = __expf(v.w);
    s += (e0 + e1) + (e2 + e3);
    tt += v.x * e0 + v.y * e1;
    tt += v.z * e2 + v.w * e3;
    s2 += v.x * w.x + v.y * w.y + v.z * w.z + v.w * w.w;
    ushort4 o;
    o.x = f2bf(v.x); o.y = f2bf(v.y); o.z = f2bf(v.z); o.w = f2bf(v.w);
    dst[lane + 64 * j] = o;
  }
  #pragma unroll
  for (int off = 32; off; off >>= 1) {
    s += __shfl_xor(s, off);
    tt += __shfl_xor(tt, off);
    s2 += __shfl_xor(s2, off);
  }
  if (lane == 0) {
    ent_t[row] = __logf(s) - tt / s;  // == m + log(sum e^{x-m}) - E_p[x]
    skq[row] = s2 + bqbk[0];
  }
}

// ---------------- softmax_fused: blocks 0..15 softmax4096 -> vew; 16..31 softmax128 -----
__global__ __launch_bounds__(1024) void softmax_fused_kernel(
    const float* __restrict__ ent_v, float* __restrict__ vew,
    const float* __restrict__ ent_t, float* __restrict__ tew) {
  __shared__ float red[32];
  __shared__ float sv[128];
  const int b = blockIdx.x, t = threadIdx.x;
  if (b < 16) {
    const float* e = ent_v + (size_t)b * N_;
    float v[4];
    float m = -__builtin_inff();
    #pragma unroll
    for (int i = 0; i < 4; i++) { v[i] = e[t + 1024 * i]; m = fmaxf(m, v[i]); }
    #pragma unroll
    for (int off = 32; off; off >>= 1) m = fmaxf(m, __shfl_xor(m, off));
    int wv = t >> 6;
    if ((t & 63) == 0) red[wv] = m;
    __syncthreads();
    if (t < 16) {
      float x = red[t];
      #pragma unroll
      for (int off = 8; off; off >>= 1) x = fmaxf(x, __shfl_xor(x, off));
      red[t] = x;
    }
    __syncthreads();
    m = red[0];
    float ev[4];
    float s = 0.f;
    #pragma unroll
    for (int i = 0; i < 4; i++) { ev[i] = __expf(v[i] - m); s += ev[i]; }
    #pragma unroll
    for (int off = 32; off; off >>= 1) s += __shfl_xor(s, off);
    __syncthreads();
    if ((t & 63) == 0) red[wv] = s;
    __syncthreads();
    if (t < 16) {
      float x = red[t];
      #pragma unroll
      for (int off = 8; off; off >>= 1) x += __shfl_xor(x, off);
      red[t] = x;
    }
    __syncthreads();
    s = red[0];
    #pragma unroll
    for (int i = 0; i < 4; i++) vew[(size_t)b * N_ + t + 1024 * i] = ev[i] / s;
  } else {
    const int bb = b - 16;
    float v = 0.f;
    if (t < 128) { v = ent_t[bb * 128 + t]; sv[t] = v; }
    __syncthreads();
    if (t < 64) {
      float m = fmaxf(sv[t], sv[t + 64]);
      #pragma unroll
      for (int off = 32; off; off >>= 1) m = fmaxf(m, __shfl_xor(m, off));
      if (t == 0) red[0] = m;
    }
    __syncthreads();
    const float m = red[0];
    float e = 0.f;
    if (t < 128) { e = __expf(v - m); sv[t] = e; }
    __syncthreads();
    if (t < 64) {
      float s = sv[t] + sv[t + 64];
      #pragma unroll
      for (int off = 32; off; off >>= 1) s += __shfl_xor(s, off);
      if (t == 0) red[1] = s;
    }
    __syncthreads();
    if (t < 128) tew[bb * 128 + t] = e / red[1];
  }
}

// ---------------- bf16 NT GEMM (BK=64): C[m,n] = sum_k A[m,k]*B[n,k], bf16 store -------
__global__ __launch_bounds__(256) void gemm_nt_kernel(
    const unsigned short* __restrict__ A, const unsigned short* __restrict__ Bm,
    unsigned short* __restrict__ C) {
  constexpr int LDA = 72;
  __shared__ unsigned short As[64 * LDA];
  __shared__ unsigned short Bs[64 * LDA];
  int m0 = blockIdx.x * 64, n0 = blockIdx.y * 64;
  int t = threadIdx.x, wave = t >> 6, lane = t & 63;
  int wm = (wave & 1) * 32, wn = (wave >> 1) * 32;
  int fl = lane & 15, fq = lane >> 4;
  f32x4 acc[2][2];
  #pragma unroll
  for (int i = 0; i < 2; i++)
    #pragma unroll
    for (int j = 0; j < 2; j++) acc[i][j] = {0.f, 0.f, 0.f, 0.f};
  for (int k0 = 0; k0 < D_; k0 += 64) {
    __syncthreads();
    #pragma unroll
    for (int i = 0; i < 2; i++) {
      int c = t + 256 * i;
      int sr = c >> 3, sc = (c & 7) * 8;
      *(uint4*)(As + sr * LDA + sc) = *(const uint4*)(A + (size_t)(m0 + sr) * D_ + k0 + sc);
      *(uint4*)(Bs + sr * LDA + sc) = *(const uint4*)(Bm + (size_t)(n0 + sr) * D_ + k0 + sc);
    }
    __syncthreads();
    #pragma unroll
    for (int ks = 0; ks < 2; ks++) {
      short8 afr[2], bfr[2];
      #pragma unroll
      for (int i = 0; i < 2; i++)
        afr[i] = *(const short8*)(As + (wm + i * 16 + fl) * LDA + ks * 32 + fq * 8);
      #pragma unroll
      for (int j = 0; j < 2; j++)
        bfr[j] = *(const short8*)(Bs + (wn + j * 16 + fl) * LDA + ks * 32 + fq * 8);
      #pragma unroll
      for (int i = 0; i < 2; i++)
        #pragma unroll
        for (int j = 0; j < 2; j++)
          acc[i][j] = __builtin_amdgcn_mfma_f32_16x16x32_bf16(afr[i], bfr[j], acc[i][j], 0, 0, 0);
    }
  }
  #pragma unroll
  for (int i = 0; i < 2; i++)
    #pragma unroll
    for (int j = 0; j < 2; j++) {
      int n = n0 + wn + j * 16 + fl;
      #pragma unroll
      for (int r = 0; r < 4; r++) {
        int m = m0 + wm + i * 16 + fq * 4 + r;
        C[(size_t)m * D_ + n] = f2bf(acc[i][j][r]);
      }
    }
}

// ---------------- merged kq (+bias2) and vT (+bv, transposed store) GEMM ----------------
__global__ __launch_bounds__(256) void gemm_kqvT_kernel(
    const unsigned short* __restrict__ A, const unsigned short* __restrict__ W2T,
    const float* __restrict__ bias2, unsigned short* __restrict__ kqb,
    const unsigned short* __restrict__ Wvb, const float* __restrict__ bv,
    unsigned short* __restrict__ vTb) {
  constexpr int LDA = 72;
  __shared__ unsigned short As[64 * LDA];
  __shared__ unsigned short Bs[64 * LDA];
  const bool isV = blockIdx.y >= 12;
  const unsigned short* Bm = isV ? Wvb : W2T;
  const float* bias = isV ? bv : bias2;
  unsigned short* C = isV ? vTb : kqb;
  int m0 = blockIdx.x * 64, n0 = (isV ? blockIdx.y - 12 : blockIdx.y) * 64;
  int t = threadIdx.x, wave = t >> 6, lane = t & 63;
  int wm = (wave & 1) * 32, wn = (wave >> 1) * 32;
  int fl = lane & 15, fq = lane >> 4;
  f32x4 acc[2][2];
  #pragma unroll
  for (int i = 0; i < 2; i++)
    #pragma unroll
    for (int j = 0; j < 2; j++) acc[i][j] = {0.f, 0.f, 0.f, 0.f};
  for (int k0 = 0; k0 < D_; k0 += 64) {
    __syncthreads();
    #pragma unroll
    for (int i = 0; i < 2; i++) {
      int c = t + 256 * i;
      int sr = c >> 3, sc = (c & 7) * 8;
      *(uint4*)(As + sr * LDA + sc) = *(const uint4*)(A + (size_t)(m0 + sr) * D_ + k0 + sc);
      *(uint4*)(Bs + sr * LDA + sc) = *(const uint4*)(Bm + (size_t)(n0 + sr) * D_ + k0 + sc);
    }
    __syncthreads();
    #pragma unroll
    for (int ks = 0; ks < 2; ks++) {
      short8 afr[2], bfr[2];
      #pragma unroll
      for (int i = 0; i < 2; i++)
        afr[i] = *(const short8*)(As + (wm + i * 16 + fl) * LDA + ks * 32 + fq * 8);
      #pragma unroll
      for (int j = 0; j < 2; j++)
        bfr[j] = *(const short8*)(Bs + (wn + j * 16 + fl) * LDA + ks * 32 + fq * 8);
      #pragma unroll
      for (int i = 0; i < 2; i++)
        #pragma unroll
        for (int j = 0; j < 2; j++)
          acc[i][j] = __builtin_amdgcn_mfma_f32_16x16x32_bf16(afr[i], bfr[j], acc[i][j], 0, 0, 0);
    }
  }
  #pragma unroll
  for (int i = 0; i < 2; i++)
    #pragma unroll
    for (int j = 0; j < 2; j++) {
      int n = n0 + wn + j * 16 + fl;
      float bb = bias[n];
      #pragma unroll
      for (int r = 0; r < 4; r++) {
        int m = m0 + wm + i * 16 + fq * 4 + r;
        float val = acc[i][j][r] + bb;
        if (isV) {
          int bt = m >> 7, q = m & 127;
          C[((size_t)bt * D_ + n) * Q_ + q] = f2bf(val);
        } else {
          C[(size_t)m * D_ + n] = f2bf(val);
        }
      }
    }
}

// ---------------- A1: S = vf*kq^T (fp32 store) + inline visual entropy ----------------
// LDS = As+Bs+esh = 37,888 B -> 4 blocks/CU. No softmax, no spin, no cross-block sync.
__global__ __launch_bounds__(256, 4) void attn_s_kernel(
    const float* __restrict__ vis,
    const unsigned short* __restrict__ kq,   // [B][Q][768] bf16
    float* __restrict__ S,                   // [B][4096][128] fp32
    float* __restrict__ ent_v)               // [B][4096]
{
  constexpr int LA = 68;
  constexpr int LB = 72;
  __shared__ unsigned short As[128 * LA];   // 17408 B
  __shared__ unsigned short Bs[128 * LB];   // 18432 B
  __shared__ float esh[512];                //  2048 B

  const int bb = blockIdx.x >> 5;
  const int n0 = (blockIdx.x & 31) * 128;
  const int t = threadIdx.x;
  const int wave = t >> 6, lane = t & 63;
  const int fl = lane & 15, fq = lane >> 4;
  const int wm = (wave & 1) * 64;   // token half
  const int wq = (wave >> 1) * 64;  // q half

  const float* abase = vis + (size_t)bb * D_ * N_ + n0;
  const unsigned short* bbase = kq + (size_t)bb * Q_ * D_;

  f32x4 acc[4][4];
  #pragma unroll
  for (int i = 0; i < 4; i++)
    #pragma unroll
    for (int j = 0; j < 4; j++) acc[i][j] = {0.f, 0.f, 0.f, 0.f};

  const int smi = t & 127;
  const int ph = t >> 7;
  // online softmax-entropy accumulators (no-max form; |v|<~6 -> fp32-safe, R1/R3-proven)
  float es = 0.f, ets = 0.f;

  for (int k0 = 0; k0 < D_; k0 += 64) {
    __syncthreads();
    // stage A (transpose fp32 [k][n] -> bf16 [m][k]) + entropy accumulation
    #pragma unroll
    for (int i = 0; i < 16; i++) {
      const int kk = 2 * (ph + 2 * i);
      const float v0 = abase[(size_t)(k0 + kk) * N_ + smi];
      const float v1 = abase[(size_t)(k0 + kk + 1) * N_ + smi];
      const float e0 = __expf(v0), e1 = __expf(v1);
      es += e0 + e1;
      ets += v0 * e0 + v1 * e1;
      const unsigned pk = (unsigned)f2bf(v0) | ((unsigned)f2bf(v1) << 16);
      *(unsigned*)(As + smi * LA + kk) = pk;
    }
    // stage B (kq rows, contiguous k)
    #pragma unroll
    for (int i = 0; i < 4; i++) {
      const int c = t + 256 * i;
      const int q = c >> 3, kc = (c & 7) * 8;
      const uint4 v = *(const uint4*)(bbase + (size_t)q * D_ + k0 + kc);
      *(uint4*)(Bs + q * LB + kc) = v;
    }
    __syncthreads();
    #pragma unroll
    for (int ks = 0; ks < 2; ks++) {
      short8 afr[4], bfr[4];
      #pragma unroll
      for (int i = 0; i < 4; i++) {
        const unsigned short* pa = As + (wm + i * 16 + fl) * LA + ks * 32 + fq * 8;
        sv4 lo = *(const sv4*)pa;
        sv4 hi = *(const sv4*)(pa + 4);
        afr[i] = __builtin_shufflevector(lo, hi, 0, 1, 2, 3, 4, 5, 6, 7);
      }
      #pragma unroll
      for (int j = 0; j < 4; j++)
        bfr[j] = *(const short8*)(Bs + (wq + j * 16 + fl) * LB + ks * 32 + fq * 8);
      #pragma unroll
      for (int i = 0; i < 4; i++)
        #pragma unroll
        for (int j = 0; j < 4; j++)
          acc[i][j] = __builtin_amdgcn_mfma_f32_16x16x32_bf16(afr[i], bfr[j], acc[i][j], 0, 0, 0);
    }
  }

  // entropy epilogue: thread t and t^128 cover complementary d-halves of token smi
  esh[t] = es;
  esh[256 + t] = ets;
  __syncthreads();
  if (t < 128) {
    const float Sx = es + esh[t + 128];
    const float Tx = ets + esh[384 + t];
    ent_v[(size_t)bb * N_ + n0 + t] = __logf(Sx) - Tx / Sx;
  }

  // S store (fp32, lossless round trip)
  float* sbase = S + ((size_t)bb * N_ + n0) * Q_;
  #pragma unroll
  for (int i = 0; i < 4; i++)
    #pragma unroll
    for (int j = 0; j < 4; j++)
      #pragma unroll
      for (int r = 0; r < 4; r++)
        sbase[(size_t)(wm + i * 16 + fq * 4 + r) * Q_ + wq + j * 16 + fl] = acc[i][j][r];
}

// ---------------- A2: softmax (entropy-modulated) + O^T = vT * P^T ----------------
// LDS = Ps(34816) + Vs(17408, stats aliased) = 52,224 B -> 3 blocks/CU.
__global__ __launch_bounds__(256, 3) void attn_pv_kernel(
    const float* __restrict__ S,             // [B][4096][128] fp32
    const unsigned short* __restrict__ vT,   // [B][768][Q] bf16
    const float* __restrict__ ve,            // [B][4096]
    const float* __restrict__ te,            // [B][128]
    const float* __restrict__ skq,           // [B*Q]
    float* __restrict__ out)                 // [B][768][4096]
{
  constexpr int LP = 136;  // P stride and V stride (q-dim 128 + pad)
  __shared__ unsigned short region0[26112];       // 52224 B
  unsigned short* Ps = region0;                   // bytes [0, 34816)
  unsigned short* Vs = region0 + 17408;           // bytes [34816, 52224)
  float* stats = (float*)(region0 + 17408);       // aliases Vs (dead until phase B)

  const int bb = blockIdx.x >> 5;
  const int n0 = (blockIdx.x & 31) * 128;
  const int t = threadIdx.x;
  const int wave = t >> 6, lane = t & 63;
  const int fl = lane & 15, fq = lane >> 4;
  const int wm = (wave & 1) * 64;   // token half
  const int wq = (wave >> 1) * 64;  // q half

  // load S tile into the MFMA-output register layout (bitwise same values as R3's acc)
  f32x4 acc[4][4];
  const float* sbase = S + ((size_t)bb * N_ + n0) * Q_;
  #pragma unroll
  for (int i = 0; i < 4; i++)
    #pragma unroll
    for (int j = 0; j < 4; j++)
      #pragma unroll
      for (int r = 0; r < 4; r++)
        acc[i][j][r] = sbase[(size_t)(wm + i * 16 + fq * 4 + r) * Q_ + wq + j * 16 + fl];

  // ---------- softmax with entropy modulation (verbatim R3) ----------
  const float rsD = 0.03608439182435161f;  // 1/sqrt(768)
  float tev[4], skv[4];
  #pragma unroll
  for (int j = 0; j < 4; j++) {
    int q = wq + j * 16 + fl;
    tev[j] = te[bb * Q_ + q];
    skv[j] = skq[bb * Q_ + q];
  }
  float vev4[4][4];
  #pragma unroll
  for (int i = 0; i < 4; i++)
    #pragma unroll
    for (int r = 0; r < 4; r++)
      vev4[i][r] = ve[(size_t)bb * N_ + n0 + wm + i * 16 + fq * 4 + r];

  float rmax[4][4], rsum[4][4];
  #pragma unroll
  for (int i = 0; i < 4; i++)
    #pragma unroll
    for (int r = 0; r < 4; r++) rmax[i][r] = -__builtin_inff();
  #pragma unroll
  for (int i = 0; i < 4; i++)
    #pragma unroll
    for (int j = 0; j < 4; j++)
      #pragma unroll
      for (int r = 0; r < 4; r++) {
        float L = (acc[i][j][r] + skv[j]) * rsD * vev4[i][r] * tev[j];
        acc[i][j][r] = L;
        rmax[i][r] = fmaxf(rmax[i][r], L);
      }
  #pragma unroll
  for (int off = 1; off < 16; off <<= 1)
    #pragma unroll
    for (int i = 0; i < 4; i++)
      #pragma unroll
      for (int r = 0; r < 4; r++)
        rmax[i][r] = fmaxf(rmax[i][r], __shfl_xor(rmax[i][r], off));
  #pragma unroll
  for (int i = 0; i < 4; i++)
    #pragma unroll
    for (int r = 0; r < 4; r++) rsum[i][r] = 0.f;
  #pragma unroll
  for (int i = 0; i < 4; i++)
    #pragma unroll
    for (int j = 0; j < 4; j++)
      #pragma unroll
      for (int r = 0; r < 4; r++) {
        float e = __expf(acc[i][j][r] - rmax[i][r]);
        acc[i][j][r] = e;
        rsum[i][r] += e;
      }
  #pragma unroll
  for (int off = 1; off < 16; off <<= 1)
    #pragma unroll
    for (int i = 0; i < 4; i++)
      #pragma unroll
      for (int r = 0; r < 4; r++) rsum[i][r] += __shfl_xor(rsum[i][r], off);

  const int qh = wq >> 6;
  if (fl == 0) {
    #pragma unroll
    for (int i = 0; i < 4; i++)
      #pragma unroll
      for (int r = 0; r < 4; r++) {
        int m = wm + i * 16 + fq * 4 + r;
        stats[(qh * 128 + m) * 2 + 0] = rmax[i][r];
        stats[(qh * 128 + m) * 2 + 1] = rsum[i][r];
      }
  }
  __syncthreads();
  float fac[4][4];
  #pragma unroll
  for (int i = 0; i < 4; i++)
    #pragma unroll
    for (int r = 0; r < 4; r++) {
      int m = wm + i * 16 + fq * 4 + r;
      float M2 = stats[((1 - qh) * 128 + m) * 2 + 0];
      float S2 = stats[((1 - qh) * 128 + m) * 2 + 1];
      float Mf = fmaxf(rmax[i][r], M2);
      float sf = rsum[i][r] * __expf(rmax[i][r] - Mf) + S2 * __expf(M2 - Mf);
      fac[i][r] = __expf(rmax[i][r] - Mf) / sf;
    }
  #pragma unroll
  for (int i = 0; i < 4; i++)
    #pragma unroll
    for (int j = 0; j < 4; j++)
      #pragma unroll
      for (int r = 0; r < 4; r++) {
        int m = wm + i * 16 + fq * 4 + r;
        int q = wq + j * 16 + fl;
        Ps[m * LP + q] = f2bf(acc[i][j][r] * fac[i][r]);
      }

  // ---------- phase B: O^T = vT * P^T, d-chunks of 64 (12 chunks) ----------
  const int wd = (wave & 1) * 32;   // d half within chunk
  const int wm2 = (wave >> 1) * 64; // token half
  for (int dc = 0; dc < 12; dc++) {
    __syncthreads();  // covers Ps writes + stats reads (dc=0) and prior-chunk Vs reads
    const unsigned short* vbase = vT + ((size_t)bb * D_ + dc * 64) * Q_;
    #pragma unroll
    for (int i = 0; i < 4; i++) {
      const int c = t + 256 * i;
      const int d = c >> 4, qc = (c & 15) * 8;
      *(uint4*)(Vs + d * LP + qc) = *(const uint4*)(vbase + (size_t)d * Q_ + qc);
    }
    __syncthreads();
    f32x4 acc2[2][4];
    #pragma unroll
    for (int i = 0; i < 2; i++)
      #pragma unroll
      for (int j = 0; j < 4; j++) acc2[i][j] = {0.f, 0.f, 0.f, 0.f};
    #pragma unroll
    for (int ks = 0; ks < 4; ks++) {
      short8 vfr[2], pfr[4];
      #pragma unroll
      for (int i = 0; i < 2; i++)
        vfr[i] = *(const short8*)(Vs + (wd + i * 16 + fl) * LP + ks * 32 + fq * 8);
      #pragma unroll
      for (int j = 0; j < 4; j++)
        pfr[j] = *(const short8*)(Ps + (wm2 + j * 16 + fl) * LP + ks * 32 + fq * 8);
      #pragma unroll
      for (int i = 0; i < 2; i++)
        #pragma unroll
        for (int j = 0; j < 4; j++)
          acc2[i][j] = __builtin_amdgcn_mfma_f32_16x16x32_bf16(vfr[i], pfr[j], acc2[i][j], 0, 0, 0);
    }
    float* obase = out + ((size_t)bb * D_ + dc * 64) * N_ + n0;
    #pragma unroll
    for (int i = 0; i < 2; i++)
      #pragma unroll
      for (int j = 0; j < 4; j++) {
        int mm = wm2 + j * 16 + fl;
        #pragma unroll
        for (int r = 0; r < 4; r++) {
          int d = wd + i * 16 + fq * 4 + r;
          obase[(size_t)d * N_ + mm] = acc2[i][j][r];
        }
      }
  }
}

extern "C" void kernel_launch(void* const* d_in, const int* in_sizes, int n_in,
                              void* d_out, int out_size, void* d_ws, size_t ws_size,
                              hipStream_t stream) {
  const float* vis  = (const float*)d_in[0];
  const float* text = (const float*)d_in[1];
  const float* Wq   = (const float*)d_in[2];
  const float* bq   = (const float*)d_in[3];
  const float* Wk   = (const float*)d_in[4];
  const float* bk   = (const float*)d_in[5];
  const float* Wv   = (const float*)d_in[6];
  const float* bv   = (const float*)d_in[7];
  float* out = (float*)d_out;
  char* ws = (char*)d_ws;

  unsigned short* textb = (unsigned short*)(ws + 0);
  unsigned short* WkTb  = (unsigned short*)(ws + 3145728);
  unsigned short* Wvb   = (unsigned short*)(ws + 4325376);
  unsigned short* WqTb  = (unsigned short*)(ws + 5505024);
  unsigned short* W2Tb  = (unsigned short*)(ws + 6684672);
  float* wkbq  = (float*)(ws + 7864320);
  float* bias2 = (float*)(ws + 7867392);
  float* bqbk  = (float*)(ws + 7870464);
  unsigned short* kqb   = (unsigned short*)(ws + 9830400);
  unsigned short* vTb   = (unsigned short*)(ws + 12976128);
  float* ent_t = (float*)(ws + 16121856);
  float* tew   = (float*)(ws + 16130048);
  float* ent_v = (float*)(ws + 16138240);
  float* vew   = (float*)(ws + 16400384);
  float* skq   = (float*)(ws + 16662528);
  float* Sbuf  = (float*)(ws + 16777216);   // 33,554,432 B -> total ws 50,331,648 B
  // (fill counters show the harness poisons 768 MiB of ws -> plenty of headroom)

  // 1. weight casts/transposes + vec-mat folds
  prep_kernel<<<dim3(24, 24, 4), 256, 0, stream>>>(Wv, Wq, Wk, bq, bk,
                                                   Wvb, WqTb, WkTb, wkbq, bias2, bqbk);
  // 2. text cast + entropy + skq
  text_prep_kernel<<<512, 256, 0, stream>>>(text, textb, ent_t, wkbq, bqbk, skq);
  // 3. W2T = (Wk^T Wq)^T
  gemm_nt_kernel<<<dim3(12, 12), 256, 0, stream>>>(WqTb, WkTb, W2Tb);
  // 4. kq = text@W2 + bias2 || vT
  gemm_kqvT_kernel<<<dim3(32, 24), 256, 0, stream>>>(textb, W2Tb, bias2, kqb, Wvb, bv, vTb);
  // 5. S = vf*kq^T + inline visual entropy (vis read exactly once)
  attn_s_kernel<<<512, 256, 0, stream>>>(vis, kqb, Sbuf, ent_v);
  // 6. softmax4096 (ve) || softmax128 (te)
  softmax_fused_kernel<<<32, 1024, 0, stream>>>(ent_v, vew, ent_t, tew);
  // 7. softmax-modulated P + PV -> out
  attn_pv_kernel<<<512, 256, 0, stream>>>(Sbuf, vTb, vew, tew, skq, out);
}

// Round 5
// 436.592 us; speedup vs baseline: 1.4537x; 1.4537x over previous
//
#include <hip/hip_runtime.h>

#define B_ 16
#define D_ 768
#define N_ 4096
#define Q_ 128

typedef __attribute__((ext_vector_type(4))) float f32x4;
typedef __attribute__((ext_vector_type(8))) short short8;
typedef __attribute__((ext_vector_type(4))) short sv4;

__device__ __forceinline__ unsigned short f2bf(float f) {
  union { float f; unsigned u; } x; x.f = f;
  unsigned u = x.u;
  unsigned r = u + 0x7fffu + ((u >> 16) & 1u);
  return (unsigned short)(r >> 16);
}
__device__ __forceinline__ float bf2f(unsigned short h) {
  union { unsigned u; float f; } x; x.u = ((unsigned)h) << 16;
  return x.f;
}

// ---------------- prep: z=0 cast Wk, z=1 cast Wv, z=2 transpose+cast Wq ----------------
__global__ __launch_bounds__(256) void prep_kernel(
    const float* __restrict__ Wk, const float* __restrict__ Wv,
    const float* __restrict__ Wq,
    unsigned short* __restrict__ Wkb, unsigned short* __restrict__ Wvb,
    unsigned short* __restrict__ WqTb) {
  __shared__ float tile[32][33];
  const int z = blockIdx.z;
  const int t = threadIdx.x;
  if (z <= 1) {
    const float* src = z ? Wv : Wk;
    unsigned short* dst = z ? Wvb : Wkb;
    int i = (blockIdx.y * 24 + blockIdx.x) * 256 + t;  // 576*256 = 768*768/4
    float4 v = ((const float4*)src)[i];
    ushort4 o;
    o.x = f2bf(v.x); o.y = f2bf(v.y); o.z = f2bf(v.z); o.w = f2bf(v.w);
    ((ushort4*)dst)[i] = o;
  } else {
    int bx = blockIdx.x * 32, by = blockIdx.y * 32;
    int tx = t & 31, ty = t >> 5;
    #pragma unroll
    for (int i = 0; i < 32; i += 8)
      tile[ty + i][tx] = Wq[(size_t)(by + ty + i) * D_ + bx + tx];
    __syncthreads();
    #pragma unroll
    for (int i = 0; i < 32; i += 8)
      WqTb[(size_t)(bx + ty + i) * D_ + by + tx] = f2bf(tile[tx][ty + i]);
  }
}

// ---------------- text prep: cast fp32->bf16 + per-row softmax-entropy ------------------
__global__ __launch_bounds__(256) void text_prep_kernel(
    const float* __restrict__ text, unsigned short* __restrict__ textb,
    float* __restrict__ ent_t) {
  int row = blockIdx.x * 4 + (threadIdx.x >> 6);
  int lane = threadIdx.x & 63;
  const float4* src = (const float4*)(text + (size_t)row * D_);
  ushort4* dst = (ushort4*)(textb + (size_t)row * D_);
  float s = 0.f, tt = 0.f;
  #pragma unroll
  for (int j = 0; j < 3; j++) {
    float4 v = src[lane + 64 * j];
    float e0 = __expf(v.x), e1 = __expf(v.y), e2 = __expf(v.z), e3 = __expf(v.w);
    s += (e0 + e1) + (e2 + e3);
    tt += v.x * e0 + v.y * e1;
    tt += v.z * e2 + v.w * e3;
    ushort4 o;
    o.x = f2bf(v.x); o.y = f2bf(v.y); o.z = f2bf(v.z); o.w = f2bf(v.w);
    dst[lane + 64 * j] = o;
  }
  #pragma unroll
  for (int off = 32; off; off >>= 1) {
    s += __shfl_xor(s, off);
    tt += __shfl_xor(tt, off);
  }
  if (lane == 0) ent_t[row] = __logf(s) - tt / s;  // == m + log(sum e^{x-m}) - E_p[x]
}

// ---------------- softmax_fused: blocks 0..15 softmax4096 -> vew; 16..31 softmax128 -----
__global__ __launch_bounds__(1024) void softmax_fused_kernel(
    const float* __restrict__ ent_v, float* __restrict__ vew,
    const float* __restrict__ ent_t, float* __restrict__ tew) {
  __shared__ float red[32];
  __shared__ float sv[128];
  const int b = blockIdx.x, t = threadIdx.x;
  if (b < 16) {
    const float* e = ent_v + (size_t)b * N_;
    float v[4];
    float m = -__builtin_inff();
    #pragma unroll
    for (int i = 0; i < 4; i++) { v[i] = e[t + 1024 * i]; m = fmaxf(m, v[i]); }
    #pragma unroll
    for (int off = 32; off; off >>= 1) m = fmaxf(m, __shfl_xor(m, off));
    int wv = t >> 6;
    if ((t & 63) == 0) red[wv] = m;
    __syncthreads();
    if (t < 16) {
      float x = red[t];
      #pragma unroll
      for (int off = 8; off; off >>= 1) x = fmaxf(x, __shfl_xor(x, off));
      red[t] = x;
    }
    __syncthreads();
    m = red[0];
    float ev[4];
    float s = 0.f;
    #pragma unroll
    for (int i = 0; i < 4; i++) { ev[i] = __expf(v[i] - m); s += ev[i]; }
    #pragma unroll
    for (int off = 32; off; off >>= 1) s += __shfl_xor(s, off);
    __syncthreads();
    if ((t & 63) == 0) red[wv] = s;
    __syncthreads();
    if (t < 16) {
      float x = red[t];
      #pragma unroll
      for (int off = 8; off; off >>= 1) x += __shfl_xor(x, off);
      red[t] = x;
    }
    __syncthreads();
    s = red[0];
    #pragma unroll
    for (int i = 0; i < 4; i++) vew[(size_t)b * N_ + t + 1024 * i] = ev[i] / s;
  } else {
    const int bb = b - 16;
    float v = 0.f;
    if (t < 128) { v = ent_t[bb * 128 + t]; sv[t] = v; }
    __syncthreads();
    if (t < 64) {
      float m = fmaxf(sv[t], sv[t + 64]);
      #pragma unroll
      for (int off = 32; off; off >>= 1) m = fmaxf(m, __shfl_xor(m, off));
      if (t == 0) red[0] = m;
    }
    __syncthreads();
    const float m = red[0];
    float e = 0.f;
    if (t < 128) { e = __expf(v - m); sv[t] = e; }
    __syncthreads();
    if (t < 64) {
      float s = sv[t] + sv[t + 64];
      #pragma unroll
      for (int off = 32; off; off >>= 1) s += __shfl_xor(s, off);
      if (t == 0) red[1] = s;
    }
    __syncthreads();
    if (t < 128) tew[bb * 128 + t] = e / red[1];
  }
}

// ---------------- merged k (+bk) and vT (+bv, transposed store) GEMM --------------------
// blockIdx.y < 12: kb = text@Wk^T + bk -> [2048][768]; else vT[b][n][q] = (text@Wv^T+bv)^T
__global__ __launch_bounds__(256) void gemm_kvT_kernel(
    const unsigned short* __restrict__ A, const unsigned short* __restrict__ Wkb,
    const float* __restrict__ bk, unsigned short* __restrict__ kb,
    const unsigned short* __restrict__ Wvb, const float* __restrict__ bv,
    unsigned short* __restrict__ vTb) {
  constexpr int LDA = 72;
  __shared__ unsigned short As[64 * LDA];
  __shared__ unsigned short Bs[64 * LDA];
  const bool isV = blockIdx.y >= 12;
  const unsigned short* Bm = isV ? Wvb : Wkb;
  const float* bias = isV ? bv : bk;
  unsigned short* C = isV ? vTb : kb;
  int m0 = blockIdx.x * 64, n0 = (isV ? blockIdx.y - 12 : blockIdx.y) * 64;
  int t = threadIdx.x, wave = t >> 6, lane = t & 63;
  int wm = (wave & 1) * 32, wn = (wave >> 1) * 32;
  int fl = lane & 15, fq = lane >> 4;
  f32x4 acc[2][2];
  #pragma unroll
  for (int i = 0; i < 2; i++)
    #pragma unroll
    for (int j = 0; j < 2; j++) acc[i][j] = {0.f, 0.f, 0.f, 0.f};
  for (int k0 = 0; k0 < D_; k0 += 64) {
    __syncthreads();
    #pragma unroll
    for (int i = 0; i < 2; i++) {
      int c = t + 256 * i;
      int sr = c >> 3, sc = (c & 7) * 8;
      *(uint4*)(As + sr * LDA + sc) = *(const uint4*)(A + (size_t)(m0 + sr) * D_ + k0 + sc);
      *(uint4*)(Bs + sr * LDA + sc) = *(const uint4*)(Bm + (size_t)(n0 + sr) * D_ + k0 + sc);
    }
    __syncthreads();
    #pragma unroll
    for (int ks = 0; ks < 2; ks++) {
      short8 afr[2], bfr[2];
      #pragma unroll
      for (int i = 0; i < 2; i++)
        afr[i] = *(const short8*)(As + (wm + i * 16 + fl) * LDA + ks * 32 + fq * 8);
      #pragma unroll
      for (int j = 0; j < 2; j++)
        bfr[j] = *(const short8*)(Bs + (wn + j * 16 + fl) * LDA + ks * 32 + fq * 8);
      #pragma unroll
      for (int i = 0; i < 2; i++)
        #pragma unroll
        for (int j = 0; j < 2; j++)
          acc[i][j] = __builtin_amdgcn_mfma_f32_16x16x32_bf16(afr[i], bfr[j], acc[i][j], 0, 0, 0);
    }
  }
  #pragma unroll
  for (int i = 0; i < 2; i++)
    #pragma unroll
    for (int j = 0; j < 2; j++) {
      int n = n0 + wn + j * 16 + fl;
      float bb = bias[n];
      #pragma unroll
      for (int r = 0; r < 4; r++) {
        int m = m0 + wm + i * 16 + fq * 4 + r;
        float val = acc[i][j][r] + bb;
        if (isV) {
          int bt = m >> 7, q = m & 127;
          C[((size_t)bt * D_ + n) * Q_ + q] = f2bf(val);
        } else {
          C[(size_t)m * D_ + n] = f2bf(val);
        }
      }
    }
}

// ---------------- merged kq GEMM (y<12) and skq bias_dot (y>=12) ------------------------
__global__ __launch_bounds__(256) void gemm_kq_bias_kernel(
    const unsigned short* __restrict__ kb, const unsigned short* __restrict__ WqTb,
    unsigned short* __restrict__ kqb, const float* __restrict__ bq,
    float* __restrict__ skq) {
  constexpr int LDA = 72;
  __shared__ unsigned short As[64 * LDA];
  __shared__ unsigned short Bs[64 * LDA];
  const int t = threadIdx.x;
  if (blockIdx.y >= 12) {
    // skq[row] = dot(bq, k[row]); one wave per row
    int idx = (blockIdx.y - 12) * 32 + blockIdx.x;   // 0..511
    int row = idx * 4 + (t >> 6);
    int lane = t & 63;
    const unsigned short* kr = kb + (size_t)row * D_;
    float s = 0.f;
    for (int k = lane; k < D_; k += 64) s += bq[k] * bf2f(kr[k]);
    #pragma unroll
    for (int off = 32; off; off >>= 1) s += __shfl_xor(s, off);
    if (lane == 0) skq[row] = s;
    return;
  }
  int m0 = blockIdx.x * 64, n0 = blockIdx.y * 64;
  int wave = t >> 6, lane = t & 63;
  int wm = (wave & 1) * 32, wn = (wave >> 1) * 32;
  int fl = lane & 15, fq = lane >> 4;
  f32x4 acc[2][2];
  #pragma unroll
  for (int i = 0; i < 2; i++)
    #pragma unroll
    for (int j = 0; j < 2; j++) acc[i][j] = {0.f, 0.f, 0.f, 0.f};
  for (int k0 = 0; k0 < D_; k0 += 64) {
    __syncthreads();
    #pragma unroll
    for (int i = 0; i < 2; i++) {
      int c = t + 256 * i;
      int sr = c >> 3, sc = (c & 7) * 8;
      *(uint4*)(As + sr * LDA + sc) = *(const uint4*)(kb + (size_t)(m0 + sr) * D_ + k0 + sc);
      *(uint4*)(Bs + sr * LDA + sc) = *(const uint4*)(WqTb + (size_t)(n0 + sr) * D_ + k0 + sc);
    }
    __syncthreads();
    #pragma unroll
    for (int ks = 0; ks < 2; ks++) {
      short8 afr[2], bfr[2];
      #pragma unroll
      for (int i = 0; i < 2; i++)
        afr[i] = *(const short8*)(As + (wm + i * 16 + fl) * LDA + ks * 32 + fq * 8);
      #pragma unroll
      for (int j = 0; j < 2; j++)
        bfr[j] = *(const short8*)(Bs + (wn + j * 16 + fl) * LDA + ks * 32 + fq * 8);
      #pragma unroll
      for (int i = 0; i < 2; i++)
        #pragma unroll
        for (int j = 0; j < 2; j++)
          acc[i][j] = __builtin_amdgcn_mfma_f32_16x16x32_bf16(afr[i], bfr[j], acc[i][j], 0, 0, 0);
    }
  }
  #pragma unroll
  for (int i = 0; i < 2; i++)
    #pragma unroll
    for (int j = 0; j < 2; j++) {
      int n = n0 + wn + j * 16 + fl;
      #pragma unroll
      for (int r = 0; r < 4; r++) {
        int m = m0 + wm + i * 16 + fq * 4 + r;
        kqb[(size_t)m * D_ + n] = f2bf(acc[i][j][r]);
      }
    }
}

// ---------------- A1: S = vf*kq^T (fp32) + inline visual entropy, 64-token blocks -------
// LDS 29,184 B; VGPR target ~110 (acc[2][4]=32) -> 4 blocks/CU with grid 1024.
__global__ __launch_bounds__(256, 2) void attn_s_kernel(
    const float* __restrict__ vis,
    const unsigned short* __restrict__ kq,   // [B][Q][768] bf16
    float* __restrict__ S,                   // [B][4096][128] fp32
    float* __restrict__ ent_v)               // [B][4096]
{
  constexpr int LA = 68;
  constexpr int LB = 72;
  __shared__ unsigned short As[64 * LA];    //  8704 B
  __shared__ unsigned short Bs[128 * LB];   // 18432 B
  __shared__ float esh[512];                //  2048 B

  const int bb = blockIdx.x >> 6;
  const int n0 = (blockIdx.x & 63) * 64;
  const int t = threadIdx.x;
  const int wave = t >> 6, lane = t & 63;
  const int fl = lane & 15, fq = lane >> 4;
  const int wm = (wave & 1) * 32;   // token half (32 of 64)
  const int wq = (wave >> 1) * 64;  // q half

  const float* abase = vis + (size_t)bb * D_ * N_ + n0;
  const unsigned short* bbase = kq + (size_t)bb * Q_ * D_;

  f32x4 acc[2][4];
  #pragma unroll
  for (int i = 0; i < 2; i++)
    #pragma unroll
    for (int j = 0; j < 4; j++) acc[i][j] = {0.f, 0.f, 0.f, 0.f};

  const int smi = t & 63;   // token within block
  const int ph = t >> 6;    // k-quarter
  // online softmax-entropy accumulators (no-max form; |v|<~6 -> fp32-safe, R1/R3-proven)
  float es = 0.f, ets = 0.f;

  for (int k0 = 0; k0 < D_; k0 += 64) {
    __syncthreads();
    // stage A: transpose fp32 [k][n] -> bf16 [tok][k] + entropy accumulation
    #pragma unroll
    for (int i = 0; i < 8; i++) {
      const int kk = 2 * (ph + 4 * i);
      const float v0 = abase[(size_t)(k0 + kk) * N_ + smi];
      const float v1 = abase[(size_t)(k0 + kk + 1) * N_ + smi];
      const float e0 = __expf(v0), e1 = __expf(v1);
      es += e0 + e1;
      ets += v0 * e0 + v1 * e1;
      const unsigned pk = (unsigned)f2bf(v0) | ((unsigned)f2bf(v1) << 16);
      *(unsigned*)(As + smi * LA + kk) = pk;
    }
    // stage B: kq rows, contiguous k (128 q x 64 k)
    #pragma unroll
    for (int i = 0; i < 4; i++) {
      const int c = t + 256 * i;
      const int q = c >> 3, kc = (c & 7) * 8;
      const uint4 v = *(const uint4*)(bbase + (size_t)q * D_ + k0 + kc);
      *(uint4*)(Bs + q * LB + kc) = v;
    }
    __syncthreads();
    #pragma unroll
    for (int ks = 0; ks < 2; ks++) {
      short8 afr[2], bfr[4];
      #pragma unroll
      for (int i = 0; i < 2; i++) {
        const unsigned short* pa = As + (wm + i * 16 + fl) * LA + ks * 32 + fq * 8;
        sv4 lo = *(const sv4*)pa;
        sv4 hi = *(const sv4*)(pa + 4);
        afr[i] = __builtin_shufflevector(lo, hi, 0, 1, 2, 3, 4, 5, 6, 7);
      }
      #pragma unroll
      for (int j = 0; j < 4; j++)
        bfr[j] = *(const short8*)(Bs + (wq + j * 16 + fl) * LB + ks * 32 + fq * 8);
      #pragma unroll
      for (int i = 0; i < 2; i++)
        #pragma unroll
        for (int j = 0; j < 4; j++)
          acc[i][j] = __builtin_amdgcn_mfma_f32_16x16x32_bf16(afr[i], bfr[j], acc[i][j], 0, 0, 0);
    }
  }

  // entropy epilogue: 4 threads (k-quarters) per token
  esh[t] = es;
  esh[256 + t] = ets;
  __syncthreads();
  if (t < 64) {
    const float Sx = esh[t] + esh[t + 64] + esh[t + 128] + esh[t + 192];
    const float Tx = esh[256 + t] + esh[320 + t] + esh[384 + t] + esh[448 + t];
    ent_v[(size_t)bb * N_ + n0 + t] = __logf(Sx) - Tx / Sx;
  }

  // S store (fp32, lossless round trip)
  float* sbase = S + ((size_t)bb * N_ + n0) * Q_;
  #pragma unroll
  for (int i = 0; i < 2; i++)
    #pragma unroll
    for (int j = 0; j < 4; j++)
      #pragma unroll
      for (int r = 0; r < 4; r++)
        sbase[(size_t)(wm + i * 16 + fq * 4 + r) * Q_ + wq + j * 16 + fl] = acc[i][j][r];
}

// ---------------- A2: softmax (entropy-modulated) + O^T = vT * P^T, 64-token blocks -----
// LDS 35,840 B -> 4 blocks/CU with grid 1024.
__global__ __launch_bounds__(256, 2) void attn_pv_kernel(
    const float* __restrict__ S,             // [B][4096][128] fp32
    const unsigned short* __restrict__ vT,   // [B][768][Q] bf16
    const float* __restrict__ ve,            // [B][4096]
    const float* __restrict__ te,            // [B][128]
    const float* __restrict__ skq,           // [B*Q]
    float* __restrict__ out)                 // [B][768][4096]
{
  constexpr int LP = 136;
  __shared__ unsigned short Ps[64 * LP];    // 17408 B
  __shared__ unsigned short Vs[64 * LP];    // 17408 B
  __shared__ float stats[2][64][2];         //  1024 B

  const int bb = blockIdx.x >> 6;
  const int n0 = (blockIdx.x & 63) * 64;
  const int t = threadIdx.x;
  const int wave = t >> 6, lane = t & 63;
  const int fl = lane & 15, fq = lane >> 4;
  const int wm = (wave & 1) * 32;   // token half
  const int wq = (wave >> 1) * 64;  // q half

  // load S tile into the MFMA-output register layout (bitwise-identical values)
  f32x4 acc[2][4];
  const float* sbase = S + ((size_t)bb * N_ + n0) * Q_;
  #pragma unroll
  for (int i = 0; i < 2; i++)
    #pragma unroll
    for (int j = 0; j < 4; j++)
      #pragma unroll
      for (int r = 0; r < 4; r++)
        acc[i][j][r] = sbase[(size_t)(wm + i * 16 + fq * 4 + r) * Q_ + wq + j * 16 + fl];

  // ---------- softmax with entropy modulation ----------
  const float rsD = 0.03608439182435161f;  // 1/sqrt(768)
  float tev[4], skv[4];
  #pragma unroll
  for (int j = 0; j < 4; j++) {
    int q = wq + j * 16 + fl;
    tev[j] = te[bb * Q_ + q];
    skv[j] = skq[bb * Q_ + q];
  }
  float vev4[2][4];
  #pragma unroll
  for (int i = 0; i < 2; i++)
    #pragma unroll
    for (int r = 0; r < 4; r++)
      vev4[i][r] = ve[(size_t)bb * N_ + n0 + wm + i * 16 + fq * 4 + r];

  float rmax[2][4], rsum[2][4];
  #pragma unroll
  for (int i = 0; i < 2; i++)
    #pragma unroll
    for (int r = 0; r < 4; r++) rmax[i][r] = -__builtin_inff();
  #pragma unroll
  for (int i = 0; i < 2; i++)
    #pragma unroll
    for (int j = 0; j < 4; j++)
      #pragma unroll
      for (int r = 0; r < 4; r++) {
        float L = (acc[i][j][r] + skv[j]) * rsD * vev4[i][r] * tev[j];
        acc[i][j][r] = L;
        rmax[i][r] = fmaxf(rmax[i][r], L);
      }
  #pragma unroll
  for (int off = 1; off < 16; off <<= 1)
    #pragma unroll
    for (int i = 0; i < 2; i++)
      #pragma unroll
      for (int r = 0; r < 4; r++)
        rmax[i][r] = fmaxf(rmax[i][r], __shfl_xor(rmax[i][r], off));
  #pragma unroll
  for (int i = 0; i < 2; i++)
    #pragma unroll
    for (int r = 0; r < 4; r++) rsum[i][r] = 0.f;
  #pragma unroll
  for (int i = 0; i < 2; i++)
    #pragma unroll
    for (int j = 0; j < 4; j++)
      #pragma unroll
      for (int r = 0; r < 4; r++) {
        float e = __expf(acc[i][j][r] - rmax[i][r]);
        acc[i][j][r] = e;
        rsum[i][r] += e;
      }
  #pragma unroll
  for (int off = 1; off < 16; off <<= 1)
    #pragma unroll
    for (int i = 0; i < 2; i++)
      #pragma unroll
      for (int r = 0; r < 4; r++) rsum[i][r] += __shfl_xor(rsum[i][r], off);

  const int qh = wq >> 6;
  if (fl == 0) {
    #pragma unroll
    for (int i = 0; i < 2; i++)
      #pragma unroll
      for (int r = 0; r < 4; r++) {
        int m = wm + i * 16 + fq * 4 + r;
        stats[qh][m][0] = rmax[i][r];
        stats[qh][m][1] = rsum[i][r];
      }
  }
  __syncthreads();
  float fac[2][4];
  #pragma unroll
  for (int i = 0; i < 2; i++)
    #pragma unroll
    for (int r = 0; r < 4; r++) {
      int m = wm + i * 16 + fq * 4 + r;
      float M2 = stats[1 - qh][m][0], S2 = stats[1 - qh][m][1];
      float Mf = fmaxf(rmax[i][r], M2);
      float sf = rsum[i][r] * __expf(rmax[i][r] - Mf) + S2 * __expf(M2 - Mf);
      fac[i][r] = __expf(rmax[i][r] - Mf) / sf;
    }
  #pragma unroll
  for (int i = 0; i < 2; i++)
    #pragma unroll
    for (int j = 0; j < 4; j++)
      #pragma unroll
      for (int r = 0; r < 4; r++) {
        int m = wm + i * 16 + fq * 4 + r;
        int q = wq + j * 16 + fl;
        Ps[m * LP + q] = f2bf(acc[i][j][r] * fac[i][r]);
      }

  // ---------- phase B: O^T = vT * P^T, d-chunks of 64 (12 chunks) ----------
  const int wd = (wave & 1) * 32;   // d half within chunk
  const int wm2 = (wave >> 1) * 32; // token half
  for (int dc = 0; dc < 12; dc++) {
    __syncthreads();  // covers Ps writes + stats reads (dc=0) and prior-chunk Vs reads
    const unsigned short* vbase = vT + ((size_t)bb * D_ + dc * 64) * Q_;
    #pragma unroll
    for (int i = 0; i < 4; i++) {
      const int c = t + 256 * i;
      const int d = c >> 4, qc = (c & 15) * 8;
      *(uint4*)(Vs + d * LP + qc) = *(const uint4*)(vbase + (size_t)d * Q_ + qc);
    }
    __syncthreads();
    f32x4 acc2[2][2];
    #pragma unroll
    for (int i = 0; i < 2; i++)
      #pragma unroll
      for (int j = 0; j < 2; j++) acc2[i][j] = {0.f, 0.f, 0.f, 0.f};
    #pragma unroll
    for (int ks = 0; ks < 4; ks++) {
      short8 vfr[2], pfr[2];
      #pragma unroll
      for (int i = 0; i < 2; i++)
        vfr[i] = *(const short8*)(Vs + (wd + i * 16 + fl) * LP + ks * 32 + fq * 8);
      #pragma unroll
      for (int j = 0; j < 2; j++)
        pfr[j] = *(const short8*)(Ps + (wm2 + j * 16 + fl) * LP + ks * 32 + fq * 8);
      #pragma unroll
      for (int i = 0; i < 2; i++)
        #pragma unroll
        for (int j = 0; j < 2; j++)
          acc2[i][j] = __builtin_amdgcn_mfma_f32_16x16x32_bf16(vfr[i], pfr[j], acc2[i][j], 0, 0, 0);
    }
    float* obase = out + ((size_t)bb * D_ + dc * 64) * N_ + n0;
    #pragma unroll
    for (int i = 0; i < 2; i++)
      #pragma unroll
      for (int j = 0; j < 2; j++) {
        int mm = wm2 + j * 16 + fl;
        #pragma unroll
        for (int r = 0; r < 4; r++) {
          int d = wd + i * 16 + fq * 4 + r;
          obase[(size_t)d * N_ + mm] = acc2[i][j][r];
        }
      }
  }
}

extern "C" void kernel_launch(void* const* d_in, const int* in_sizes, int n_in,
                              void* d_out, int out_size, void* d_ws, size_t ws_size,
                              hipStream_t stream) {
  const float* vis  = (const float*)d_in[0];
  const float* text = (const float*)d_in[1];
  const float* Wq   = (const float*)d_in[2];
  const float* bq   = (const float*)d_in[3];
  const float* Wk   = (const float*)d_in[4];
  const float* bk   = (const float*)d_in[5];
  const float* Wv   = (const float*)d_in[6];
  const float* bv   = (const float*)d_in[7];
  float* out = (float*)d_out;
  char* ws = (char*)d_ws;

  unsigned short* textb = (unsigned short*)(ws + 0);
  unsigned short* Wkb   = (unsigned short*)(ws + 3145728);
  unsigned short* Wvb   = (unsigned short*)(ws + 4325376);
  unsigned short* WqTb  = (unsigned short*)(ws + 5505024);
  unsigned short* kb    = (unsigned short*)(ws + 6684672);
  unsigned short* kqb   = (unsigned short*)(ws + 9830400);
  unsigned short* vTb   = (unsigned short*)(ws + 12976128);
  float* ent_t = (float*)(ws + 16121856);
  float* tew   = (float*)(ws + 16130048);
  float* ent_v = (float*)(ws + 16138240);
  float* vew   = (float*)(ws + 16400384);
  float* skq   = (float*)(ws + 16662528);
  float* Sbuf  = (float*)(ws + 16777216);   // 33,554,432 B -> total ws 50,331,648 B

  // 1. weight casts + Wq transpose
  prep_kernel<<<dim3(24, 24, 3), 256, 0, stream>>>(Wk, Wv, Wq, Wkb, Wvb, WqTb);
  // 2. text cast + entropy
  text_prep_kernel<<<512, 256, 0, stream>>>(text, textb, ent_t);
  // 3. k = text@Wk^T + bk || vT = (text@Wv^T + bv)^T
  gemm_kvT_kernel<<<dim3(32, 24), 256, 0, stream>>>(textb, Wkb, bk, kb, Wvb, bv, vTb);
  // 4. kq = k@Wq || skq = k@bq
  gemm_kq_bias_kernel<<<dim3(32, 28), 256, 0, stream>>>(kb, WqTb, kqb, bq, skq);
  // 5. S = vf*kq^T + inline visual entropy (vis read exactly once)
  attn_s_kernel<<<1024, 256, 0, stream>>>(vis, kqb, Sbuf, ent_v);
  // 6. softmax4096 (ve) || softmax128 (te)
  softmax_fused_kernel<<<32, 1024, 0, stream>>>(ent_v, vew, ent_t, tew);
  // 7. softmax-modulated P + PV -> out
  attn_pv_kernel<<<1024, 256, 0, stream>>>(Sbuf, vTb, vew, tew, skq, out);
}

// Round 6
// 435.858 us; speedup vs baseline: 1.4562x; 1.0017x over previous
//
#include <hip/hip_runtime.h>
#include <hip/hip_cooperative_groups.h>

#define B_ 16
#define D_ 768
#define N_ 4096
#define Q_ 128

typedef __attribute__((ext_vector_type(4))) float f32x4;
typedef __attribute__((ext_vector_type(8))) short short8;
typedef __attribute__((ext_vector_type(4))) short sv4;

__device__ __forceinline__ unsigned short f2bf(float f) {
  union { float f; unsigned u; } x; x.f = f;
  unsigned u = x.u;
  unsigned r = u + 0x7fffu + ((u >> 16) & 1u);
  return (unsigned short)(r >> 16);
}
__device__ __forceinline__ float bf2f(unsigned short h) {
  union { unsigned u; float f; } x; x.u = ((unsigned)h) << 16;
  return x.f;
}

// ---------------- prep: z=0 cast Wk, z=1 cast Wv, z=2 transpose+cast Wq ----------------
// block (0,0,2) also zeroes the per-batch Zb accumulators used by attn_fused.
__global__ __launch_bounds__(256) void prep_kernel(
    const float* __restrict__ Wk, const float* __restrict__ Wv,
    const float* __restrict__ Wq,
    unsigned short* __restrict__ Wkb, unsigned short* __restrict__ Wvb,
    unsigned short* __restrict__ WqTb, float* __restrict__ Zb) {
  __shared__ float tile[32][33];
  const int z = blockIdx.z;
  const int t = threadIdx.x;
  if (z <= 1) {
    const float* src = z ? Wv : Wk;
    unsigned short* dst = z ? Wvb : Wkb;
    int i = (blockIdx.y * 24 + blockIdx.x) * 256 + t;  // 576*256 = 768*768/4
    float4 v = ((const float4*)src)[i];
    ushort4 o;
    o.x = f2bf(v.x); o.y = f2bf(v.y); o.z = f2bf(v.z); o.w = f2bf(v.w);
    ((ushort4*)dst)[i] = o;
  } else {
    int bx = blockIdx.x * 32, by = blockIdx.y * 32;
    int tx = t & 31, ty = t >> 5;
    #pragma unroll
    for (int i = 0; i < 32; i += 8)
      tile[ty + i][tx] = Wq[(size_t)(by + ty + i) * D_ + bx + tx];
    __syncthreads();
    #pragma unroll
    for (int i = 0; i < 32; i += 8)
      WqTb[(size_t)(bx + ty + i) * D_ + by + tx] = f2bf(tile[tx][ty + i]);
    if (blockIdx.x == 0 && blockIdx.y == 0 && t < 16) Zb[t] = 0.f;
  }
}

// ---------------- text prep: cast fp32->bf16 + per-row softmax-entropy ------------------
__global__ __launch_bounds__(256) void text_prep_kernel(
    const float* __restrict__ text, unsigned short* __restrict__ textb,
    float* __restrict__ ent_t) {
  int row = blockIdx.x * 4 + (threadIdx.x >> 6);
  int lane = threadIdx.x & 63;
  const float4* src = (const float4*)(text + (size_t)row * D_);
  ushort4* dst = (ushort4*)(textb + (size_t)row * D_);
  float s = 0.f, tt = 0.f;
  #pragma unroll
  for (int j = 0; j < 3; j++) {
    float4 v = src[lane + 64 * j];
    float e0 = __expf(v.x), e1 = __expf(v.y), e2 = __expf(v.z), e3 = __expf(v.w);
    s += (e0 + e1) + (e2 + e3);
    tt += v.x * e0 + v.y * e1;
    tt += v.z * e2 + v.w * e3;
    ushort4 o;
    o.x = f2bf(v.x); o.y = f2bf(v.y); o.z = f2bf(v.z); o.w = f2bf(v.w);
    dst[lane + 64 * j] = o;
  }
  #pragma unroll
  for (int off = 32; off; off >>= 1) {
    s += __shfl_xor(s, off);
    tt += __shfl_xor(tt, off);
  }
  if (lane == 0) ent_t[row] = __logf(s) - tt / s;  // == m + log(sum e^{x-m}) - E_p[x]
}

// ---------------- softmax_fused (FALLBACK): 0..15 softmax4096; 16..31 softmax128 --------
__global__ __launch_bounds__(1024) void softmax_fused_kernel(
    const float* __restrict__ ent_v, float* __restrict__ vew,
    const float* __restrict__ ent_t, float* __restrict__ tew) {
  __shared__ float red[32];
  __shared__ float sv[128];
  const int b = blockIdx.x, t = threadIdx.x;
  if (b < 16) {
    const float* e = ent_v + (size_t)b * N_;
    float v[4];
    float m = -__builtin_inff();
    #pragma unroll
    for (int i = 0; i < 4; i++) { v[i] = e[t + 1024 * i]; m = fmaxf(m, v[i]); }
    #pragma unroll
    for (int off = 32; off; off >>= 1) m = fmaxf(m, __shfl_xor(m, off));
    int wv = t >> 6;
    if ((t & 63) == 0) red[wv] = m;
    __syncthreads();
    if (t < 16) {
      float x = red[t];
      #pragma unroll
      for (int off = 8; off; off >>= 1) x = fmaxf(x, __shfl_xor(x, off));
      red[t] = x;
    }
    __syncthreads();
    m = red[0];
    float ev[4];
    float s = 0.f;
    #pragma unroll
    for (int i = 0; i < 4; i++) { ev[i] = __expf(v[i] - m); s += ev[i]; }
    #pragma unroll
    for (int off = 32; off; off >>= 1) s += __shfl_xor(s, off);
    __syncthreads();
    if ((t & 63) == 0) red[wv] = s;
    __syncthreads();
    if (t < 16) {
      float x = red[t];
      #pragma unroll
      for (int off = 8; off; off >>= 1) x += __shfl_xor(x, off);
      red[t] = x;
    }
    __syncthreads();
    s = red[0];
    #pragma unroll
    for (int i = 0; i < 4; i++) vew[(size_t)b * N_ + t + 1024 * i] = ev[i] / s;
  } else {
    const int bb = b - 16;
    float v = 0.f;
    if (t < 128) { v = ent_t[bb * 128 + t]; sv[t] = v; }
    __syncthreads();
    if (t < 64) {
      float m = fmaxf(sv[t], sv[t + 64]);
      #pragma unroll
      for (int off = 32; off; off >>= 1) m = fmaxf(m, __shfl_xor(m, off));
      if (t == 0) red[0] = m;
    }
    __syncthreads();
    const float m = red[0];
    float e = 0.f;
    if (t < 128) { e = __expf(v - m); sv[t] = e; }
    __syncthreads();
    if (t < 64) {
      float s = sv[t] + sv[t + 64];
      #pragma unroll
      for (int off = 32; off; off >>= 1) s += __shfl_xor(s, off);
      if (t == 0) red[1] = s;
    }
    __syncthreads();
    if (t < 128) tew[bb * 128 + t] = e / red[1];
  }
}

// ---------------- merged k (+bk) and vT (+bv, transposed store) GEMM --------------------
__global__ __launch_bounds__(256) void gemm_kvT_kernel(
    const unsigned short* __restrict__ A, const unsigned short* __restrict__ Wkb,
    const float* __restrict__ bk, unsigned short* __restrict__ kb,
    const unsigned short* __restrict__ Wvb, const float* __restrict__ bv,
    unsigned short* __restrict__ vTb) {
  constexpr int LDA = 72;
  __shared__ unsigned short As[64 * LDA];
  __shared__ unsigned short Bs[64 * LDA];
  const bool isV = blockIdx.y >= 12;
  const unsigned short* Bm = isV ? Wvb : Wkb;
  const float* bias = isV ? bv : bk;
  unsigned short* C = isV ? vTb : kb;
  int m0 = blockIdx.x * 64, n0 = (isV ? blockIdx.y - 12 : blockIdx.y) * 64;
  int t = threadIdx.x, wave = t >> 6, lane = t & 63;
  int wm = (wave & 1) * 32, wn = (wave >> 1) * 32;
  int fl = lane & 15, fq = lane >> 4;
  f32x4 acc[2][2];
  #pragma unroll
  for (int i = 0; i < 2; i++)
    #pragma unroll
    for (int j = 0; j < 2; j++) acc[i][j] = {0.f, 0.f, 0.f, 0.f};
  for (int k0 = 0; k0 < D_; k0 += 64) {
    __syncthreads();
    #pragma unroll
    for (int i = 0; i < 2; i++) {
      int c = t + 256 * i;
      int sr = c >> 3, sc = (c & 7) * 8;
      *(uint4*)(As + sr * LDA + sc) = *(const uint4*)(A + (size_t)(m0 + sr) * D_ + k0 + sc);
      *(uint4*)(Bs + sr * LDA + sc) = *(const uint4*)(Bm + (size_t)(n0 + sr) * D_ + k0 + sc);
    }
    __syncthreads();
    #pragma unroll
    for (int ks = 0; ks < 2; ks++) {
      short8 afr[2], bfr[2];
      #pragma unroll
      for (int i = 0; i < 2; i++)
        afr[i] = *(const short8*)(As + (wm + i * 16 + fl) * LDA + ks * 32 + fq * 8);
      #pragma unroll
      for (int j = 0; j < 2; j++)
        bfr[j] = *(const short8*)(Bs + (wn + j * 16 + fl) * LDA + ks * 32 + fq * 8);
      #pragma unroll
      for (int i = 0; i < 2; i++)
        #pragma unroll
        for (int j = 0; j < 2; j++)
          acc[i][j] = __builtin_amdgcn_mfma_f32_16x16x32_bf16(afr[i], bfr[j], acc[i][j], 0, 0, 0);
    }
  }
  #pragma unroll
  for (int i = 0; i < 2; i++)
    #pragma unroll
    for (int j = 0; j < 2; j++) {
      int n = n0 + wn + j * 16 + fl;
      float bb = bias[n];
      #pragma unroll
      for (int r = 0; r < 4; r++) {
        int m = m0 + wm + i * 16 + fq * 4 + r;
        float val = acc[i][j][r] + bb;
        if (isV) {
          int bt = m >> 7, q = m & 127;
          C[((size_t)bt * D_ + n) * Q_ + q] = f2bf(val);
        } else {
          C[(size_t)m * D_ + n] = f2bf(val);
        }
      }
    }
}

// ---------------- merged kq GEMM (y<12) and skq bias_dot (y>=12) ------------------------
__global__ __launch_bounds__(256) void gemm_kq_bias_kernel(
    const unsigned short* __restrict__ kb, const unsigned short* __restrict__ WqTb,
    unsigned short* __restrict__ kqb, const float* __restrict__ bq,
    float* __restrict__ skq) {
  constexpr int LDA = 72;
  __shared__ unsigned short As[64 * LDA];
  __shared__ unsigned short Bs[64 * LDA];
  const int t = threadIdx.x;
  if (blockIdx.y >= 12) {
    int idx = (blockIdx.y - 12) * 32 + blockIdx.x;   // 0..511
    int row = idx * 4 + (t >> 6);
    int lane = t & 63;
    const unsigned short* kr = kb + (size_t)row * D_;
    float s = 0.f;
    for (int k = lane; k < D_; k += 64) s += bq[k] * bf2f(kr[k]);
    #pragma unroll
    for (int off = 32; off; off >>= 1) s += __shfl_xor(s, off);
    if (lane == 0) skq[row] = s;
    return;
  }
  int m0 = blockIdx.x * 64, n0 = blockIdx.y * 64;
  int wave = t >> 6, lane = t & 63;
  int wm = (wave & 1) * 32, wn = (wave >> 1) * 32;
  int fl = lane & 15, fq = lane >> 4;
  f32x4 acc[2][2];
  #pragma unroll
  for (int i = 0; i < 2; i++)
    #pragma unroll
    for (int j = 0; j < 2; j++) acc[i][j] = {0.f, 0.f, 0.f, 0.f};
  for (int k0 = 0; k0 < D_; k0 += 64) {
    __syncthreads();
    #pragma unroll
    for (int i = 0; i < 2; i++) {
      int c = t + 256 * i;
      int sr = c >> 3, sc = (c & 7) * 8;
      *(uint4*)(As + sr * LDA + sc) = *(const uint4*)(kb + (size_t)(m0 + sr) * D_ + k0 + sc);
      *(uint4*)(Bs + sr * LDA + sc) = *(const uint4*)(WqTb + (size_t)(n0 + sr) * D_ + k0 + sc);
    }
    __syncthreads();
    #pragma unroll
    for (int ks = 0; ks < 2; ks++) {
      short8 afr[2], bfr[2];
      #pragma unroll
      for (int i = 0; i < 2; i++)
        afr[i] = *(const short8*)(As + (wm + i * 16 + fl) * LDA + ks * 32 + fq * 8);
      #pragma unroll
      for (int j = 0; j < 2; j++)
        bfr[j] = *(const short8*)(Bs + (wn + j * 16 + fl) * LDA + ks * 32 + fq * 8);
      #pragma unroll
      for (int i = 0; i < 2; i++)
        #pragma unroll
        for (int j = 0; j < 2; j++)
          acc[i][j] = __builtin_amdgcn_mfma_f32_16x16x32_bf16(afr[i], bfr[j], acc[i][j], 0, 0, 0);
    }
  }
  #pragma unroll
  for (int i = 0; i < 2; i++)
    #pragma unroll
    for (int j = 0; j < 2; j++) {
      int n = n0 + wn + j * 16 + fl;
      #pragma unroll
      for (int r = 0; r < 4; r++) {
        int m = m0 + wm + i * 16 + fq * 4 + r;
        kqb[(size_t)m * D_ + n] = f2bf(acc[i][j][r]);
      }
    }
}

// ---------------- FUSED attention: S in regs, grid.sync for Z_b, then PV ----------------
// 64-token blocks, grid 1024 = 4 blocks/CU x 256 CU (checked at launch via occupancy API).
// LDS: region0 34816 + stats 1024 + tesh 512 + vesh 256 + zsh/tsum 8 = 36,616 B.
__global__ __launch_bounds__(256, 2) void attn_fused_kernel(
    const float* __restrict__ vis,
    const unsigned short* __restrict__ kq,   // [B][Q][768] bf16
    const unsigned short* __restrict__ vT,   // [B][768][Q] bf16
    const float* __restrict__ ent_t,         // [B*128]
    const float* __restrict__ skq,           // [B*Q]
    float* __restrict__ Zb,                  // [B] atomic accum of sum exp(ent_v)
    float* __restrict__ out)                 // [B][768][4096]
{
  constexpr int LA = 68;
  constexpr int LB = 72;
  constexpr int LP = 136;
  __shared__ unsigned short region0[17408];  // 34816 B
  __shared__ float stats[2][64][2];          //  1024 B
  __shared__ float tesh[128];                //   512 B
  __shared__ float vesh[64];                 //   256 B
  __shared__ float zsh, tsum;
  unsigned short* As = region0;              // phase A: [0, 8704) B
  unsigned short* Bs = region0 + 4352;       // phase A: [8704, 27136) B
  float* esh = (float*)(region0 + 13568);    // epilogue: [27136, 29184) B
  unsigned short* Ps = region0;              // phase B: [0, 17408) B
  unsigned short* Vs = region0 + 8704;       // phase B: [17408, 34816) B

  const int bb = blockIdx.x >> 6;
  const int n0 = (blockIdx.x & 63) * 64;
  const int t = threadIdx.x;
  const int wave = t >> 6, lane = t & 63;
  const int fl = lane & 15, fq = lane >> 4;
  const int wm = (wave & 1) * 32;   // token half (32 of 64)
  const int wq = (wave >> 1) * 64;  // q half

  // ---- te = softmax(ent_t[bb]) computed block-locally (no-max form; ent ~ 6) ----
  if (t < 128) tesh[t] = __expf(ent_t[bb * 128 + t]);
  __syncthreads();
  if (t < 64) {
    float s = tesh[t] + tesh[t + 64];
    #pragma unroll
    for (int off = 32; off; off >>= 1) s += __shfl_xor(s, off);
    if (t == 0) tsum = s;
  }

  const float* abase = vis + (size_t)bb * D_ * N_ + n0;
  const unsigned short* bbase = kq + (size_t)bb * Q_ * D_;

  f32x4 acc[2][4];
  #pragma unroll
  for (int i = 0; i < 2; i++)
    #pragma unroll
    for (int j = 0; j < 4; j++) acc[i][j] = {0.f, 0.f, 0.f, 0.f};

  const int smi = t & 63;   // token within block
  const int ph = t >> 6;    // k-quarter
  float es = 0.f, ets = 0.f;  // online softmax-entropy (no-max; fp32-safe for |v|<~6)

  // ---------- phase A: S = vf * kq^T ----------
  for (int k0 = 0; k0 < D_; k0 += 64) {
    __syncthreads();
    #pragma unroll
    for (int i = 0; i < 8; i++) {
      const int kk = 2 * (ph + 4 * i);
      const float v0 = abase[(size_t)(k0 + kk) * N_ + smi];
      const float v1 = abase[(size_t)(k0 + kk + 1) * N_ + smi];
      const float e0 = __expf(v0), e1 = __expf(v1);
      es += e0 + e1;
      ets += v0 * e0 + v1 * e1;
      const unsigned pk = (unsigned)f2bf(v0) | ((unsigned)f2bf(v1) << 16);
      *(unsigned*)(As + smi * LA + kk) = pk;
    }
    #pragma unroll
    for (int i = 0; i < 4; i++) {
      const int c = t + 256 * i;
      const int q = c >> 3, kc = (c & 7) * 8;
      const uint4 v = *(const uint4*)(bbase + (size_t)q * D_ + k0 + kc);
      *(uint4*)(Bs + q * LB + kc) = v;
    }
    __syncthreads();
    #pragma unroll
    for (int ks = 0; ks < 2; ks++) {
      short8 afr[2], bfr[4];
      #pragma unroll
      for (int i = 0; i < 2; i++) {
        const unsigned short* pa = As + (wm + i * 16 + fl) * LA + ks * 32 + fq * 8;
        sv4 lo = *(const sv4*)pa;
        sv4 hi = *(const sv4*)(pa + 4);
        afr[i] = __builtin_shufflevector(lo, hi, 0, 1, 2, 3, 4, 5, 6, 7);
      }
      #pragma unroll
      for (int j = 0; j < 4; j++)
        bfr[j] = *(const short8*)(Bs + (wq + j * 16 + fl) * LB + ks * 32 + fq * 8);
      #pragma unroll
      for (int i = 0; i < 2; i++)
        #pragma unroll
        for (int j = 0; j < 4; j++)
          acc[i][j] = __builtin_amdgcn_mfma_f32_16x16x32_bf16(afr[i], bfr[j], acc[i][j], 0, 0, 0);
    }
  }

  // ---------- visual entropy epilogue + per-batch Z accumulation ----------
  __syncthreads();              // all As/Bs reads done before esh (aliased) writes
  esh[t] = es;
  esh[256 + t] = ets;
  __syncthreads();
  if (t < 64) {
    const float Sx = esh[t] + esh[t + 64] + esh[t + 128] + esh[t + 192];
    const float Tx = esh[256 + t] + esh[320 + t] + esh[384 + t] + esh[448 + t];
    const float ent = __logf(Sx) - Tx / Sx;
    const float ev = __expf(ent);
    vesh[t] = ev;
    float s = ev;
    #pragma unroll
    for (int off = 32; off; off >>= 1) s += __shfl_xor(s, off);
    if (t == 0) {
      atomicAdd(&Zb[bb], s);    // device-scope (default for global atomics)
      __threadfence();
    }
  }
  // ---------- grid-wide barrier: all 64 blocks of every batch have added to Zb ----------
  cooperative_groups::this_grid().sync();
  if (t == 0) zsh = atomicAdd(&Zb[bb], 0.0f);  // coherent read of final Z
  __syncthreads();
  const float rZ = 1.0f / zsh;
  const float rT = 1.0f / tsum;

  // ---------- softmax with entropy modulation (R5 attn_pv verbatim, local ve/te) --------
  const float rsD = 0.03608439182435161f;  // 1/sqrt(768)
  float tev[4], skv[4];
  #pragma unroll
  for (int j = 0; j < 4; j++) {
    int q = wq + j * 16 + fl;
    tev[j] = tesh[q] * rT;
    skv[j] = skq[bb * Q_ + q];
  }
  float vev4[2][4];
  #pragma unroll
  for (int i = 0; i < 2; i++)
    #pragma unroll
    for (int r = 0; r < 4; r++)
      vev4[i][r] = vesh[wm + i * 16 + fq * 4 + r] * rZ;

  float rmax[2][4], rsum[2][4];
  #pragma unroll
  for (int i = 0; i < 2; i++)
    #pragma unroll
    for (int r = 0; r < 4; r++) rmax[i][r] = -__builtin_inff();
  #pragma unroll
  for (int i = 0; i < 2; i++)
    #pragma unroll
    for (int j = 0; j < 4; j++)
      #pragma unroll
      for (int r = 0; r < 4; r++) {
        float L = (acc[i][j][r] + skv[j]) * rsD * vev4[i][r] * tev[j];
        acc[i][j][r] = L;
        rmax[i][r] = fmaxf(rmax[i][r], L);
      }
  #pragma unroll
  for (int off = 1; off < 16; off <<= 1)
    #pragma unroll
    for (int i = 0; i < 2; i++)
      #pragma unroll
      for (int r = 0; r < 4; r++)
        rmax[i][r] = fmaxf(rmax[i][r], __shfl_xor(rmax[i][r], off));
  #pragma unroll
  for (int i = 0; i < 2; i++)
    #pragma unroll
    for (int r = 0; r < 4; r++) rsum[i][r] = 0.f;
  #pragma unroll
  for (int i = 0; i < 2; i++)
    #pragma unroll
    for (int j = 0; j < 4; j++)
      #pragma unroll
      for (int r = 0; r < 4; r++) {
        float e = __expf(acc[i][j][r] - rmax[i][r]);
        acc[i][j][r] = e;
        rsum[i][r] += e;
      }
  #pragma unroll
  for (int off = 1; off < 16; off <<= 1)
    #pragma unroll
    for (int i = 0; i < 2; i++)
      #pragma unroll
      for (int r = 0; r < 4; r++) rsum[i][r] += __shfl_xor(rsum[i][r], off);

  const int qh = wq >> 6;
  if (fl == 0) {
    #pragma unroll
    for (int i = 0; i < 2; i++)
      #pragma unroll
      for (int r = 0; r < 4; r++) {
        int m = wm + i * 16 + fq * 4 + r;
        stats[qh][m][0] = rmax[i][r];
        stats[qh][m][1] = rsum[i][r];
      }
  }
  __syncthreads();
  float fac[2][4];
  #pragma unroll
  for (int i = 0; i < 2; i++)
    #pragma unroll
    for (int r = 0; r < 4; r++) {
      int m = wm + i * 16 + fq * 4 + r;
      float M2 = stats[1 - qh][m][0], S2 = stats[1 - qh][m][1];
      float Mf = fmaxf(rmax[i][r], M2);
      float sf = rsum[i][r] * __expf(rmax[i][r] - Mf) + S2 * __expf(M2 - Mf);
      fac[i][r] = __expf(rmax[i][r] - Mf) / sf;
    }
  #pragma unroll
  for (int i = 0; i < 2; i++)
    #pragma unroll
    for (int j = 0; j < 4; j++)
      #pragma unroll
      for (int r = 0; r < 4; r++) {
        int m = wm + i * 16 + fq * 4 + r;
        int q = wq + j * 16 + fl;
        Ps[m * LP + q] = f2bf(acc[i][j][r] * fac[i][r]);
      }

  // ---------- phase B: O^T = vT * P^T, d-chunks of 64 (12 chunks) ----------
  const int wd = (wave & 1) * 32;
  const int wm2 = (wave >> 1) * 32;
  for (int dc = 0; dc < 12; dc++) {
    __syncthreads();
    const unsigned short* vbase = vT + ((size_t)bb * D_ + dc * 64) * Q_;
    #pragma unroll
    for (int i = 0; i < 4; i++) {
      const int c = t + 256 * i;
      const int d = c >> 4, qc = (c & 15) * 8;
      *(uint4*)(Vs + d * LP + qc) = *(const uint4*)(vbase + (size_t)d * Q_ + qc);
    }
    __syncthreads();
    f32x4 acc2[2][2];
    #pragma unroll
    for (int i = 0; i < 2; i++)
      #pragma unroll
      for (int j = 0; j < 2; j++) acc2[i][j] = {0.f, 0.f, 0.f, 0.f};
    #pragma unroll
    for (int ks = 0; ks < 4; ks++) {
      short8 vfr[2], pfr[2];
      #pragma unroll
      for (int i = 0; i < 2; i++)
        vfr[i] = *(const short8*)(Vs + (wd + i * 16 + fl) * LP + ks * 32 + fq * 8);
      #pragma unroll
      for (int j = 0; j < 2; j++)
        pfr[j] = *(const short8*)(Ps + (wm2 + j * 16 + fl) * LP + ks * 32 + fq * 8);
      #pragma unroll
      for (int i = 0; i < 2; i++)
        #pragma unroll
        for (int j = 0; j < 2; j++)
          acc2[i][j] = __builtin_amdgcn_mfma_f32_16x16x32_bf16(vfr[i], pfr[j], acc2[i][j], 0, 0, 0);
    }
    float* obase = out + ((size_t)bb * D_ + dc * 64) * N_ + n0;
    #pragma unroll
    for (int i = 0; i < 2; i++)
      #pragma unroll
      for (int j = 0; j < 2; j++) {
        int mm = wm2 + j * 16 + fl;
        #pragma unroll
        for (int r = 0; r < 4; r++) {
          int d = wd + i * 16 + fq * 4 + r;
          obase[(size_t)d * N_ + mm] = acc2[i][j][r];
        }
      }
  }
}

// ---------------- A1 (FALLBACK): S = vf*kq^T (fp32) + inline visual entropy -------------
__global__ __launch_bounds__(256, 2) void attn_s_kernel(
    const float* __restrict__ vis,
    const unsigned short* __restrict__ kq,
    float* __restrict__ S,
    float* __restrict__ ent_v)
{
  constexpr int LA = 68;
  constexpr int LB = 72;
  __shared__ unsigned short As[64 * LA];
  __shared__ unsigned short Bs[128 * LB];
  __shared__ float esh[512];

  const int bb = blockIdx.x >> 6;
  const int n0 = (blockIdx.x & 63) * 64;
  const int t = threadIdx.x;
  const int wave = t >> 6, lane = t & 63;
  const int fl = lane & 15, fq = lane >> 4;
  const int wm = (wave & 1) * 32;
  const int wq = (wave >> 1) * 64;

  const float* abase = vis + (size_t)bb * D_ * N_ + n0;
  const unsigned short* bbase = kq + (size_t)bb * Q_ * D_;

  f32x4 acc[2][4];
  #pragma unroll
  for (int i = 0; i < 2; i++)
    #pragma unroll
    for (int j = 0; j < 4; j++) acc[i][j] = {0.f, 0.f, 0.f, 0.f};

  const int smi = t & 63;
  const int ph = t >> 6;
  float es = 0.f, ets = 0.f;

  for (int k0 = 0; k0 < D_; k0 += 64) {
    __syncthreads();
    #pragma unroll
    for (int i = 0; i < 8; i++) {
      const int kk = 2 * (ph + 4 * i);
      const float v0 = abase[(size_t)(k0 + kk) * N_ + smi];
      const float v1 = abase[(size_t)(k0 + kk + 1) * N_ + smi];
      const float e0 = __expf(v0), e1 = __expf(v1);
      es += e0 + e1;
      ets += v0 * e0 + v1 * e1;
      const unsigned pk = (unsigned)f2bf(v0) | ((unsigned)f2bf(v1) << 16);
      *(unsigned*)(As + smi * LA + kk) = pk;
    }
    #pragma unroll
    for (int i = 0; i < 4; i++) {
      const int c = t + 256 * i;
      const int q = c >> 3, kc = (c & 7) * 8;
      const uint4 v = *(const uint4*)(bbase + (size_t)q * D_ + k0 + kc);
      *(uint4*)(Bs + q * LB + kc) = v;
    }
    __syncthreads();
    #pragma unroll
    for (int ks = 0; ks < 2; ks++) {
      short8 afr[2], bfr[4];
      #pragma unroll
      for (int i = 0; i < 2; i++) {
        const unsigned short* pa = As + (wm + i * 16 + fl) * LA + ks * 32 + fq * 8;
        sv4 lo = *(const sv4*)pa;
        sv4 hi = *(const sv4*)(pa + 4);
        afr[i] = __builtin_shufflevector(lo, hi, 0, 1, 2, 3, 4, 5, 6, 7);
      }
      #pragma unroll
      for (int j = 0; j < 4; j++)
        bfr[j] = *(const short8*)(Bs + (wq + j * 16 + fl) * LB + ks * 32 + fq * 8);
      #pragma unroll
      for (int i = 0; i < 2; i++)
        #pragma unroll
        for (int j = 0; j < 4; j++)
          acc[i][j] = __builtin_amdgcn_mfma_f32_16x16x32_bf16(afr[i], bfr[j], acc[i][j], 0, 0, 0);
    }
  }

  esh[t] = es;
  esh[256 + t] = ets;
  __syncthreads();
  if (t < 64) {
    const float Sx = esh[t] + esh[t + 64] + esh[t + 128] + esh[t + 192];
    const float Tx = esh[256 + t] + esh[320 + t] + esh[384 + t] + esh[448 + t];
    ent_v[(size_t)bb * N_ + n0 + t] = __logf(Sx) - Tx / Sx;
  }

  float* sbase = S + ((size_t)bb * N_ + n0) * Q_;
  #pragma unroll
  for (int i = 0; i < 2; i++)
    #pragma unroll
    for (int j = 0; j < 4; j++)
      #pragma unroll
      for (int r = 0; r < 4; r++)
        sbase[(size_t)(wm + i * 16 + fq * 4 + r) * Q_ + wq + j * 16 + fl] = acc[i][j][r];
}

// ---------------- A2 (FALLBACK): softmax + O^T = vT * P^T ----------------
__global__ __launch_bounds__(256, 2) void attn_pv_kernel(
    const float* __restrict__ S,
    const unsigned short* __restrict__ vT,
    const float* __restrict__ ve,
    const float* __restrict__ te,
    const float* __restrict__ skq,
    float* __restrict__ out)
{
  constexpr int LP = 136;
  __shared__ unsigned short Ps[64 * LP];
  __shared__ unsigned short Vs[64 * LP];
  __shared__ float stats[2][64][2];

  const int bb = blockIdx.x >> 6;
  const int n0 = (blockIdx.x & 63) * 64;
  const int t = threadIdx.x;
  const int wave = t >> 6, lane = t & 63;
  const int fl = lane & 15, fq = lane >> 4;
  const int wm = (wave & 1) * 32;
  const int wq = (wave >> 1) * 64;

  f32x4 acc[2][4];
  const float* sbase = S + ((size_t)bb * N_ + n0) * Q_;
  #pragma unroll
  for (int i = 0; i < 2; i++)
    #pragma unroll
    for (int j = 0; j < 4; j++)
      #pragma unroll
      for (int r = 0; r < 4; r++)
        acc[i][j][r] = sbase[(size_t)(wm + i * 16 + fq * 4 + r) * Q_ + wq + j * 16 + fl];

  const float rsD = 0.03608439182435161f;
  float tev[4], skv[4];
  #pragma unroll
  for (int j = 0; j < 4; j++) {
    int q = wq + j * 16 + fl;
    tev[j] = te[bb * Q_ + q];
    skv[j] = skq[bb * Q_ + q];
  }
  float vev4[2][4];
  #pragma unroll
  for (int i = 0; i < 2; i++)
    #pragma unroll
    for (int r = 0; r < 4; r++)
      vev4[i][r] = ve[(size_t)bb * N_ + n0 + wm + i * 16 + fq * 4 + r];

  float rmax[2][4], rsum[2][4];
  #pragma unroll
  for (int i = 0; i < 2; i++)
    #pragma unroll
    for (int r = 0; r < 4; r++) rmax[i][r] = -__builtin_inff();
  #pragma unroll
  for (int i = 0; i < 2; i++)
    #pragma unroll
    for (int j = 0; j < 4; j++)
      #pragma unroll
      for (int r = 0; r < 4; r++) {
        float L = (acc[i][j][r] + skv[j]) * rsD * vev4[i][r] * tev[j];
        acc[i][j][r] = L;
        rmax[i][r] = fmaxf(rmax[i][r], L);
      }
  #pragma unroll
  for (int off = 1; off < 16; off <<= 1)
    #pragma unroll
    for (int i = 0; i < 2; i++)
      #pragma unroll
      for (int r = 0; r < 4; r++)
        rmax[i][r] = fmaxf(rmax[i][r], __shfl_xor(rmax[i][r], off));
  #pragma unroll
  for (int i = 0; i < 2; i++)
    #pragma unroll
    for (int r = 0; r < 4; r++) rsum[i][r] = 0.f;
  #pragma unroll
  for (int i = 0; i < 2; i++)
    #pragma unroll
    for (int j = 0; j < 4; j++)
      #pragma unroll
      for (int r = 0; r < 4; r++) {
        float e = __expf(acc[i][j][r] - rmax[i][r]);
        acc[i][j][r] = e;
        rsum[i][r] += e;
      }
  #pragma unroll
  for (int off = 1; off < 16; off <<= 1)
    #pragma unroll
    for (int i = 0; i < 2; i++)
      #pragma unroll
      for (int r = 0; r < 4; r++) rsum[i][r] += __shfl_xor(rsum[i][r], off);

  const int qh = wq >> 6;
  if (fl == 0) {
    #pragma unroll
    for (int i = 0; i < 2; i++)
      #pragma unroll
      for (int r = 0; r < 4; r++) {
        int m = wm + i * 16 + fq * 4 + r;
        stats[qh][m][0] = rmax[i][r];
        stats[qh][m][1] = rsum[i][r];
      }
  }
  __syncthreads();
  float fac[2][4];
  #pragma unroll
  for (int i = 0; i < 2; i++)
    #pragma unroll
    for (int r = 0; r < 4; r++) {
      int m = wm + i * 16 + fq * 4 + r;
      float M2 = stats[1 - qh][m][0], S2 = stats[1 - qh][m][1];
      float Mf = fmaxf(rmax[i][r], M2);
      float sf = rsum[i][r] * __expf(rmax[i][r] - Mf) + S2 * __expf(M2 - Mf);
      fac[i][r] = __expf(rmax[i][r] - Mf) / sf;
    }
  #pragma unroll
  for (int i = 0; i < 2; i++)
    #pragma unroll
    for (int j = 0; j < 4; j++)
      #pragma unroll
      for (int r = 0; r < 4; r++) {
        int m = wm + i * 16 + fq * 4 + r;
        int q = wq + j * 16 + fl;
        Ps[m * LP + q] = f2bf(acc[i][j][r] * fac[i][r]);
      }

  const int wd = (wave & 1) * 32;
  const int wm2 = (wave >> 1) * 32;
  for (int dc = 0; dc < 12; dc++) {
    __syncthreads();
    const unsigned short* vbase = vT + ((size_t)bb * D_ + dc * 64) * Q_;
    #pragma unroll
    for (int i = 0; i < 4; i++) {
      const int c = t + 256 * i;
      const int d = c >> 4, qc = (c & 15) * 8;
      *(uint4*)(Vs + d * LP + qc) = *(const uint4*)(vbase + (size_t)d * Q_ + qc);
    }
    __syncthreads();
    f32x4 acc2[2][2];
    #pragma unroll
    for (int i = 0; i < 2; i++)
      #pragma unroll
      for (int j = 0; j < 2; j++) acc2[i][j] = {0.f, 0.f, 0.f, 0.f};
    #pragma unroll
    for (int ks = 0; ks < 4; ks++) {
      short8 vfr[2], pfr[2];
      #pragma unroll
      for (int i = 0; i < 2; i++)
        vfr[i] = *(const short8*)(Vs + (wd + i * 16 + fl) * LP + ks * 32 + fq * 8);
      #pragma unroll
      for (int j = 0; j < 2; j++)
        pfr[j] = *(const short8*)(Ps + (wm2 + j * 16 + fl) * LP + ks * 32 + fq * 8);
      #pragma unroll
      for (int i = 0; i < 2; i++)
        #pragma unroll
        for (int j = 0; j < 2; j++)
          acc2[i][j] = __builtin_amdgcn_mfma_f32_16x16x32_bf16(vfr[i], pfr[j], acc2[i][j], 0, 0, 0);
    }
    float* obase = out + ((size_t)bb * D_ + dc * 64) * N_ + n0;
    #pragma unroll
    for (int i = 0; i < 2; i++)
      #pragma unroll
      for (int j = 0; j < 2; j++) {
        int mm = wm2 + j * 16 + fl;
        #pragma unroll
        for (int r = 0; r < 4; r++) {
          int d = wd + i * 16 + fq * 4 + r;
          obase[(size_t)d * N_ + mm] = acc2[i][j][r];
        }
      }
  }
}

extern "C" void kernel_launch(void* const* d_in, const int* in_sizes, int n_in,
                              void* d_out, int out_size, void* d_ws, size_t ws_size,
                              hipStream_t stream) {
  const float* vis  = (const float*)d_in[0];
  const float* text = (const float*)d_in[1];
  const float* Wq   = (const float*)d_in[2];
  const float* bq   = (const float*)d_in[3];
  const float* Wk   = (const float*)d_in[4];
  const float* bk   = (const float*)d_in[5];
  const float* Wv   = (const float*)d_in[6];
  const float* bv   = (const float*)d_in[7];
  float* out = (float*)d_out;
  char* ws = (char*)d_ws;

  unsigned short* textb = (unsigned short*)(ws + 0);
  unsigned short* Wkb   = (unsigned short*)(ws + 3145728);
  unsigned short* Wvb   = (unsigned short*)(ws + 4325376);
  unsigned short* WqTb  = (unsigned short*)(ws + 5505024);
  unsigned short* kb    = (unsigned short*)(ws + 6684672);
  unsigned short* kqb   = (unsigned short*)(ws + 9830400);
  unsigned short* vTb   = (unsigned short*)(ws + 12976128);
  float* ent_t = (float*)(ws + 16121856);
  float* tew   = (float*)(ws + 16130048);
  float* ent_v = (float*)(ws + 16138240);
  float* vew   = (float*)(ws + 16400384);
  float* skq   = (float*)(ws + 16662528);
  float* Zb    = (float*)(ws + 16664576);
  float* Sbuf  = (float*)(ws + 16777216);   // fallback only

  // 1. weight casts + Wq transpose (+ Zb zero)
  prep_kernel<<<dim3(24, 24, 3), 256, 0, stream>>>(Wk, Wv, Wq, Wkb, Wvb, WqTb, Zb);
  // 2. text cast + entropy
  text_prep_kernel<<<512, 256, 0, stream>>>(text, textb, ent_t);
  // 3. k = text@Wk^T + bk || vT = (text@Wv^T + bv)^T
  gemm_kvT_kernel<<<dim3(32, 24), 256, 0, stream>>>(textb, Wkb, bk, kb, Wvb, bv, vTb);
  // 4. kq = k@Wq || skq = k@bq
  gemm_kq_bias_kernel<<<dim3(32, 28), 256, 0, stream>>>(kb, WqTb, kqb, bq, skq);

  // 5. fused attention (cooperative) if the whole 1024-block grid is co-resident
  int blocksPerCU = 0;
  hipOccupancyMaxActiveBlocksPerMultiprocessor(&blocksPerCU,
      (const void*)attn_fused_kernel, 256, 0);
  bool coop = blocksPerCU >= 4;
  if (coop) {
    void* args[] = {(void*)&vis, (void*)&kqb, (void*)&vTb, (void*)&ent_t,
                    (void*)&skq, (void*)&Zb, (void*)&out};
    hipError_t ce = hipLaunchCooperativeKernel((const void*)attn_fused_kernel,
                                               dim3(1024), dim3(256), args, 0, stream);
    if (ce != hipSuccess) { coop = false; (void)hipGetLastError(); }
  }
  if (!coop) {
    // fallback: verbatim R5 path
    attn_s_kernel<<<1024, 256, 0, stream>>>(vis, kqb, Sbuf, ent_v);
    softmax_fused_kernel<<<32, 1024, 0, stream>>>(ent_v, vew, ent_t, tew);
    attn_pv_kernel<<<1024, 256, 0, stream>>>(Sbuf, vTb, vew, tew, skq, out);
  }
}

// Round 7
// 430.670 us; speedup vs baseline: 1.4737x; 1.0120x over previous
//
#include <hip/hip_runtime.h>

#define B_ 16
#define D_ 768
#define N_ 4096
#define Q_ 128

typedef __attribute__((ext_vector_type(4))) float f32x4;
typedef __attribute__((ext_vector_type(8))) short short8;
typedef __attribute__((ext_vector_type(4))) short sv4;

__device__ __forceinline__ unsigned short f2bf(float f) {
  union { float f; unsigned u; } x; x.f = f;
  unsigned u = x.u;
  unsigned r = u + 0x7fffu + ((u >> 16) & 1u);
  return (unsigned short)(r >> 16);
}
__device__ __forceinline__ float bf2f(unsigned short h) {
  union { unsigned u; float f; } x; x.u = ((unsigned)h) << 16;
  return x.f;
}

// ---- prep: z=0 cast Wk, z=1 cast Wv, z=2 transpose+cast Wq, z=3 text cast+entropy ----
__global__ __launch_bounds__(256) void prep_kernel(
    const float* __restrict__ Wk, const float* __restrict__ Wv,
    const float* __restrict__ Wq, const float* __restrict__ text,
    unsigned short* __restrict__ Wkb, unsigned short* __restrict__ Wvb,
    unsigned short* __restrict__ WqTb, unsigned short* __restrict__ textb,
    float* __restrict__ ent_t) {
  __shared__ float tile[32][33];
  const int z = blockIdx.z;
  const int t = threadIdx.x;
  if (z <= 1) {
    const float* src = z ? Wv : Wk;
    unsigned short* dst = z ? Wvb : Wkb;
    int i = (blockIdx.y * 24 + blockIdx.x) * 256 + t;  // 576*256 = 768*768/4
    float4 v = ((const float4*)src)[i];
    ushort4 o;
    o.x = f2bf(v.x); o.y = f2bf(v.y); o.z = f2bf(v.z); o.w = f2bf(v.w);
    ((ushort4*)dst)[i] = o;
  } else if (z == 2) {
    int bx = blockIdx.x * 32, by = blockIdx.y * 32;
    int tx = t & 31, ty = t >> 5;
    #pragma unroll
    for (int i = 0; i < 32; i += 8)
      tile[ty + i][tx] = Wq[(size_t)(by + ty + i) * D_ + bx + tx];
    __syncthreads();
    #pragma unroll
    for (int i = 0; i < 32; i += 8)
      WqTb[(size_t)(bx + ty + i) * D_ + by + tx] = f2bf(tile[tx][ty + i]);
  } else {
    // text: cast fp32->bf16 + per-row softmax-entropy; 512 of 576 blocks used
    int idx = blockIdx.y * 24 + blockIdx.x;
    if (idx >= 512) return;
    int row = idx * 4 + (t >> 6);
    int lane = t & 63;
    const float4* src = (const float4*)(text + (size_t)row * D_);
    ushort4* dst = (ushort4*)(textb + (size_t)row * D_);
    float s = 0.f, tt = 0.f;
    #pragma unroll
    for (int j = 0; j < 3; j++) {
      float4 v = src[lane + 64 * j];
      float e0 = __expf(v.x), e1 = __expf(v.y), e2 = __expf(v.z), e3 = __expf(v.w);
      s += (e0 + e1) + (e2 + e3);
      tt += v.x * e0 + v.y * e1;
      tt += v.z * e2 + v.w * e3;
      ushort4 o;
      o.x = f2bf(v.x); o.y = f2bf(v.y); o.z = f2bf(v.z); o.w = f2bf(v.w);
      dst[lane + 64 * j] = o;
    }
    #pragma unroll
    for (int off = 32; off; off >>= 1) {
      s += __shfl_xor(s, off);
      tt += __shfl_xor(tt, off);
    }
    if (lane == 0) ent_t[row] = __logf(s) - tt / s;  // m + log(sum e^{x-m}) - E_p[x]
  }
}

// ---------------- merged k (+bk) and vT (+bv, transposed store) GEMM --------------------
__global__ __launch_bounds__(256) void gemm_kvT_kernel(
    const unsigned short* __restrict__ A, const unsigned short* __restrict__ Wkb,
    const float* __restrict__ bk, unsigned short* __restrict__ kb,
    const unsigned short* __restrict__ Wvb, const float* __restrict__ bv,
    unsigned short* __restrict__ vTb) {
  constexpr int LDA = 72;
  __shared__ unsigned short As[64 * LDA];
  __shared__ unsigned short Bs[64 * LDA];
  const bool isV = blockIdx.y >= 12;
  const unsigned short* Bm = isV ? Wvb : Wkb;
  const float* bias = isV ? bv : bk;
  unsigned short* C = isV ? vTb : kb;
  int m0 = blockIdx.x * 64, n0 = (isV ? blockIdx.y - 12 : blockIdx.y) * 64;
  int t = threadIdx.x, wave = t >> 6, lane = t & 63;
  int wm = (wave & 1) * 32, wn = (wave >> 1) * 32;
  int fl = lane & 15, fq = lane >> 4;
  f32x4 acc[2][2];
  #pragma unroll
  for (int i = 0; i < 2; i++)
    #pragma unroll
    for (int j = 0; j < 2; j++) acc[i][j] = {0.f, 0.f, 0.f, 0.f};
  for (int k0 = 0; k0 < D_; k0 += 64) {
    __syncthreads();
    #pragma unroll
    for (int i = 0; i < 2; i++) {
      int c = t + 256 * i;
      int sr = c >> 3, sc = (c & 7) * 8;
      *(uint4*)(As + sr * LDA + sc) = *(const uint4*)(A + (size_t)(m0 + sr) * D_ + k0 + sc);
      *(uint4*)(Bs + sr * LDA + sc) = *(const uint4*)(Bm + (size_t)(n0 + sr) * D_ + k0 + sc);
    }
    __syncthreads();
    #pragma unroll
    for (int ks = 0; ks < 2; ks++) {
      short8 afr[2], bfr[2];
      #pragma unroll
      for (int i = 0; i < 2; i++)
        afr[i] = *(const short8*)(As + (wm + i * 16 + fl) * LDA + ks * 32 + fq * 8);
      #pragma unroll
      for (int j = 0; j < 2; j++)
        bfr[j] = *(const short8*)(Bs + (wn + j * 16 + fl) * LDA + ks * 32 + fq * 8);
      #pragma unroll
      for (int i = 0; i < 2; i++)
        #pragma unroll
        for (int j = 0; j < 2; j++)
          acc[i][j] = __builtin_amdgcn_mfma_f32_16x16x32_bf16(afr[i], bfr[j], acc[i][j], 0, 0, 0);
    }
  }
  #pragma unroll
  for (int i = 0; i < 2; i++)
    #pragma unroll
    for (int j = 0; j < 2; j++) {
      int n = n0 + wn + j * 16 + fl;
      float bb = bias[n];
      #pragma unroll
      for (int r = 0; r < 4; r++) {
        int m = m0 + wm + i * 16 + fq * 4 + r;
        float val = acc[i][j][r] + bb;
        if (isV) {
          int bt = m >> 7, q = m & 127;
          C[((size_t)bt * D_ + n) * Q_ + q] = f2bf(val);
        } else {
          C[(size_t)m * D_ + n] = f2bf(val);
        }
      }
    }
}

// ---------------- merged kq GEMM (y<12) and skq bias_dot (y>=12) ------------------------
__global__ __launch_bounds__(256) void gemm_kq_bias_kernel(
    const unsigned short* __restrict__ kb, const unsigned short* __restrict__ WqTb,
    unsigned short* __restrict__ kqb, const float* __restrict__ bq,
    float* __restrict__ skq) {
  constexpr int LDA = 72;
  __shared__ unsigned short As[64 * LDA];
  __shared__ unsigned short Bs[64 * LDA];
  const int t = threadIdx.x;
  if (blockIdx.y >= 12) {
    int idx = (blockIdx.y - 12) * 32 + blockIdx.x;   // 0..511
    int row = idx * 4 + (t >> 6);
    int lane = t & 63;
    const unsigned short* kr = kb + (size_t)row * D_;
    float s = 0.f;
    for (int k = lane; k < D_; k += 64) s += bq[k] * bf2f(kr[k]);
    #pragma unroll
    for (int off = 32; off; off >>= 1) s += __shfl_xor(s, off);
    if (lane == 0) skq[row] = s;
    return;
  }
  int m0 = blockIdx.x * 64, n0 = blockIdx.y * 64;
  int wave = t >> 6, lane = t & 63;
  int wm = (wave & 1) * 32, wn = (wave >> 1) * 32;
  int fl = lane & 15, fq = lane >> 4;
  f32x4 acc[2][2];
  #pragma unroll
  for (int i = 0; i < 2; i++)
    #pragma unroll
    for (int j = 0; j < 2; j++) acc[i][j] = {0.f, 0.f, 0.f, 0.f};
  for (int k0 = 0; k0 < D_; k0 += 64) {
    __syncthreads();
    #pragma unroll
    for (int i = 0; i < 2; i++) {
      int c = t + 256 * i;
      int sr = c >> 3, sc = (c & 7) * 8;
      *(uint4*)(As + sr * LDA + sc) = *(const uint4*)(kb + (size_t)(m0 + sr) * D_ + k0 + sc);
      *(uint4*)(Bs + sr * LDA + sc) = *(const uint4*)(WqTb + (size_t)(n0 + sr) * D_ + k0 + sc);
    }
    __syncthreads();
    #pragma unroll
    for (int ks = 0; ks < 2; ks++) {
      short8 afr[2], bfr[2];
      #pragma unroll
      for (int i = 0; i < 2; i++)
        afr[i] = *(const short8*)(As + (wm + i * 16 + fl) * LDA + ks * 32 + fq * 8);
      #pragma unroll
      for (int j = 0; j < 2; j++)
        bfr[j] = *(const short8*)(Bs + (wn + j * 16 + fl) * LDA + ks * 32 + fq * 8);
      #pragma unroll
      for (int i = 0; i < 2; i++)
        #pragma unroll
        for (int j = 0; j < 2; j++)
          acc[i][j] = __builtin_amdgcn_mfma_f32_16x16x32_bf16(afr[i], bfr[j], acc[i][j], 0, 0, 0);
    }
  }
  #pragma unroll
  for (int i = 0; i < 2; i++)
    #pragma unroll
    for (int j = 0; j < 2; j++) {
      int n = n0 + wn + j * 16 + fl;
      #pragma unroll
      for (int r = 0; r < 4; r++) {
        int m = m0 + wm + i * 16 + fq * 4 + r;
        kqb[(size_t)m * D_ + n] = f2bf(acc[i][j][r]);
      }
    }
}

// ---------------- A1: S = vf*kq^T (fp32) + inline visual entropy, 64-token blocks -------
__global__ __launch_bounds__(256, 2) void attn_s_kernel(
    const float* __restrict__ vis,
    const unsigned short* __restrict__ kq,   // [B][Q][768] bf16
    float* __restrict__ S,                   // [B][4096][128] fp32
    float* __restrict__ ent_v)               // [B][4096]
{
  constexpr int LA = 68;
  constexpr int LB = 72;
  __shared__ unsigned short As[64 * LA];    //  8704 B
  __shared__ unsigned short Bs[128 * LB];   // 18432 B
  __shared__ float esh[512];                //  2048 B

  const int bb = blockIdx.x >> 6;
  const int n0 = (blockIdx.x & 63) * 64;
  const int t = threadIdx.x;
  const int wave = t >> 6, lane = t & 63;
  const int fl = lane & 15, fq = lane >> 4;
  const int wm = (wave & 1) * 32;   // token half (32 of 64)
  const int wq = (wave >> 1) * 64;  // q half

  const float* abase = vis + (size_t)bb * D_ * N_ + n0;
  const unsigned short* bbase = kq + (size_t)bb * Q_ * D_;

  f32x4 acc[2][4];
  #pragma unroll
  for (int i = 0; i < 2; i++)
    #pragma unroll
    for (int j = 0; j < 4; j++) acc[i][j] = {0.f, 0.f, 0.f, 0.f};

  const int smi = t & 63;   // token within block
  const int ph = t >> 6;    // k-quarter
  float es = 0.f, ets = 0.f;  // online softmax-entropy (no-max; fp32-safe for |v|<~6)

  for (int k0 = 0; k0 < D_; k0 += 64) {
    __syncthreads();
    #pragma unroll
    for (int i = 0; i < 8; i++) {
      const int kk = 2 * (ph + 4 * i);
      const float v0 = abase[(size_t)(k0 + kk) * N_ + smi];
      const float v1 = abase[(size_t)(k0 + kk + 1) * N_ + smi];
      const float e0 = __expf(v0), e1 = __expf(v1);
      es += e0 + e1;
      ets += v0 * e0 + v1 * e1;
      const unsigned pk = (unsigned)f2bf(v0) | ((unsigned)f2bf(v1) << 16);
      *(unsigned*)(As + smi * LA + kk) = pk;
    }
    #pragma unroll
    for (int i = 0; i < 4; i++) {
      const int c = t + 256 * i;
      const int q = c >> 3, kc = (c & 7) * 8;
      const uint4 v = *(const uint4*)(bbase + (size_t)q * D_ + k0 + kc);
      *(uint4*)(Bs + q * LB + kc) = v;
    }
    __syncthreads();
    #pragma unroll
    for (int ks = 0; ks < 2; ks++) {
      short8 afr[2], bfr[4];
      #pragma unroll
      for (int i = 0; i < 2; i++) {
        const unsigned short* pa = As + (wm + i * 16 + fl) * LA + ks * 32 + fq * 8;
        sv4 lo = *(const sv4*)pa;
        sv4 hi = *(const sv4*)(pa + 4);
        afr[i] = __builtin_shufflevector(lo, hi, 0, 1, 2, 3, 4, 5, 6, 7);
      }
      #pragma unroll
      for (int j = 0; j < 4; j++)
        bfr[j] = *(const short8*)(Bs + (wq + j * 16 + fl) * LB + ks * 32 + fq * 8);
      #pragma unroll
      for (int i = 0; i < 2; i++)
        #pragma unroll
        for (int j = 0; j < 4; j++)
          acc[i][j] = __builtin_amdgcn_mfma_f32_16x16x32_bf16(afr[i], bfr[j], acc[i][j], 0, 0, 0);
    }
  }

  // entropy epilogue: 4 threads (k-quarters) per token
  esh[t] = es;
  esh[256 + t] = ets;
  __syncthreads();
  if (t < 64) {
    const float Sx = esh[t] + esh[t + 64] + esh[t + 128] + esh[t + 192];
    const float Tx = esh[256 + t] + esh[320 + t] + esh[384 + t] + esh[448 + t];
    ent_v[(size_t)bb * N_ + n0 + t] = __logf(Sx) - Tx / Sx;
  }

  // S store (fp32, lossless round trip)
  float* sbase = S + ((size_t)bb * N_ + n0) * Q_;
  #pragma unroll
  for (int i = 0; i < 2; i++)
    #pragma unroll
    for (int j = 0; j < 4; j++)
      #pragma unroll
      for (int r = 0; r < 4; r++)
        sbase[(size_t)(wm + i * 16 + fq * 4 + r) * Q_ + wq + j * 16 + fl] = acc[i][j][r];
}

// ---------------- A2: block-local ve/te softmax + modulated softmax + PV ----------------
// ve/te normalizers recomputed per block from ent_v/ent_t (16.5 KB L2-resident reads,
// mathematically identical to the separate softmax kernel; no-max form, ent ~ 7).
__global__ __launch_bounds__(256, 2) void attn_pv_kernel(
    const float* __restrict__ S,             // [B][4096][128] fp32
    const unsigned short* __restrict__ vT,   // [B][768][Q] bf16
    const float* __restrict__ ent_v,         // [B*4096]
    const float* __restrict__ ent_t,         // [B*128]
    const float* __restrict__ skq,           // [B*Q]
    float* __restrict__ out)                 // [B][768][4096]
{
  constexpr int LP = 136;
  __shared__ unsigned short Ps[64 * LP];    // 17408 B
  __shared__ unsigned short Vs[64 * LP];    // 17408 B
  __shared__ float stats[2][64][2];         //  1024 B
  __shared__ float tesh[128];               //   512 B
  __shared__ float vesh[64];                //   256 B
  __shared__ float zred[4];
  __shared__ float zsum, tsum;

  const int bb = blockIdx.x >> 6;
  const int n0 = (blockIdx.x & 63) * 64;
  const int t = threadIdx.x;
  const int wave = t >> 6, lane = t & 63;
  const int fl = lane & 15, fq = lane >> 4;
  const int wm = (wave & 1) * 32;   // token half
  const int wq = (wave >> 1) * 64;  // q half

  // ---- block-local ve/te normalizers ----
  const float* evb = ent_v + (size_t)bb * N_;
  float zp = 0.f;
  #pragma unroll
  for (int i = 0; i < 16; i++) zp += __expf(evb[t + 256 * i]);
  #pragma unroll
  for (int off = 32; off; off >>= 1) zp += __shfl_xor(zp, off);
  if (lane == 0) zred[wave] = zp;
  if (t < 128) tesh[t] = __expf(ent_t[bb * 128 + t]);
  if (t < 64) vesh[t] = __expf(evb[n0 + t]);
  __syncthreads();
  if (t == 0) zsum = zred[0] + zred[1] + zred[2] + zred[3];
  if (t < 64) {
    float s = tesh[t] + tesh[t + 64];
    #pragma unroll
    for (int off = 32; off; off >>= 1) s += __shfl_xor(s, off);
    if (t == 0) tsum = s;
  }
  __syncthreads();
  const float rZ = 1.0f / zsum;
  const float rT = 1.0f / tsum;

  // load S tile into the MFMA-output register layout (bitwise-identical values)
  f32x4 acc[2][4];
  const float* sbase = S + ((size_t)bb * N_ + n0) * Q_;
  #pragma unroll
  for (int i = 0; i < 2; i++)
    #pragma unroll
    for (int j = 0; j < 4; j++)
      #pragma unroll
      for (int r = 0; r < 4; r++)
        acc[i][j][r] = sbase[(size_t)(wm + i * 16 + fq * 4 + r) * Q_ + wq + j * 16 + fl];

  // ---------- softmax with entropy modulation ----------
  const float rsD = 0.03608439182435161f;  // 1/sqrt(768)
  float tev[4], skv[4];
  #pragma unroll
  for (int j = 0; j < 4; j++) {
    int q = wq + j * 16 + fl;
    tev[j] = tesh[q] * rT;
    skv[j] = skq[bb * Q_ + q];
  }
  float vev4[2][4];
  #pragma unroll
  for (int i = 0; i < 2; i++)
    #pragma unroll
    for (int r = 0; r < 4; r++)
      vev4[i][r] = vesh[wm + i * 16 + fq * 4 + r] * rZ;

  float rmax[2][4], rsum[2][4];
  #pragma unroll
  for (int i = 0; i < 2; i++)
    #pragma unroll
    for (int r = 0; r < 4; r++) rmax[i][r] = -__builtin_inff();
  #pragma unroll
  for (int i = 0; i < 2; i++)
    #pragma unroll
    for (int j = 0; j < 4; j++)
      #pragma unroll
      for (int r = 0; r < 4; r++) {
        float L = (acc[i][j][r] + skv[j]) * rsD * vev4[i][r] * tev[j];
        acc[i][j][r] = L;
        rmax[i][r] = fmaxf(rmax[i][r], L);
      }
  #pragma unroll
  for (int off = 1; off < 16; off <<= 1)
    #pragma unroll
    for (int i = 0; i < 2; i++)
      #pragma unroll
      for (int r = 0; r < 4; r++)
        rmax[i][r] = fmaxf(rmax[i][r], __shfl_xor(rmax[i][r], off));
  #pragma unroll
  for (int i = 0; i < 2; i++)
    #pragma unroll
    for (int r = 0; r < 4; r++) rsum[i][r] = 0.f;
  #pragma unroll
  for (int i = 0; i < 2; i++)
    #pragma unroll
    for (int j = 0; j < 4; j++)
      #pragma unroll
      for (int r = 0; r < 4; r++) {
        float e = __expf(acc[i][j][r] - rmax[i][r]);
        acc[i][j][r] = e;
        rsum[i][r] += e;
      }
  #pragma unroll
  for (int off = 1; off < 16; off <<= 1)
    #pragma unroll
    for (int i = 0; i < 2; i++)
      #pragma unroll
      for (int r = 0; r < 4; r++) rsum[i][r] += __shfl_xor(rsum[i][r], off);

  const int qh = wq >> 6;
  if (fl == 0) {
    #pragma unroll
    for (int i = 0; i < 2; i++)
      #pragma unroll
      for (int r = 0; r < 4; r++) {
        int m = wm + i * 16 + fq * 4 + r;
        stats[qh][m][0] = rmax[i][r];
        stats[qh][m][1] = rsum[i][r];
      }
  }
  __syncthreads();
  float fac[2][4];
  #pragma unroll
  for (int i = 0; i < 2; i++)
    #pragma unroll
    for (int r = 0; r < 4; r++) {
      int m = wm + i * 16 + fq * 4 + r;
      float M2 = stats[1 - qh][m][0], S2 = stats[1 - qh][m][1];
      float Mf = fmaxf(rmax[i][r], M2);
      float sf = rsum[i][r] * __expf(rmax[i][r] - Mf) + S2 * __expf(M2 - Mf);
      fac[i][r] = __expf(rmax[i][r] - Mf) / sf;
    }
  #pragma unroll
  for (int i = 0; i < 2; i++)
    #pragma unroll
    for (int j = 0; j < 4; j++)
      #pragma unroll
      for (int r = 0; r < 4; r++) {
        int m = wm + i * 16 + fq * 4 + r;
        int q = wq + j * 16 + fl;
        Ps[m * LP + q] = f2bf(acc[i][j][r] * fac[i][r]);
      }

  // ---------- phase B: O^T = vT * P^T, d-chunks of 64 (12 chunks) ----------
  const int wd = (wave & 1) * 32;
  const int wm2 = (wave >> 1) * 32;
  for (int dc = 0; dc < 12; dc++) {
    __syncthreads();
    const unsigned short* vbase = vT + ((size_t)bb * D_ + dc * 64) * Q_;
    #pragma unroll
    for (int i = 0; i < 4; i++) {
      const int c = t + 256 * i;
      const int d = c >> 4, qc = (c & 15) * 8;
      *(uint4*)(Vs + d * LP + qc) = *(const uint4*)(vbase + (size_t)d * Q_ + qc);
    }
    __syncthreads();
    f32x4 acc2[2][2];
    #pragma unroll
    for (int i = 0; i < 2; i++)
      #pragma unroll
      for (int j = 0; j < 2; j++) acc2[i][j] = {0.f, 0.f, 0.f, 0.f};
    #pragma unroll
    for (int ks = 0; ks < 4; ks++) {
      short8 vfr[2], pfr[2];
      #pragma unroll
      for (int i = 0; i < 2; i++)
        vfr[i] = *(const short8*)(Vs + (wd + i * 16 + fl) * LP + ks * 32 + fq * 8);
      #pragma unroll
      for (int j = 0; j < 2; j++)
        pfr[j] = *(const short8*)(Ps + (wm2 + j * 16 + fl) * LP + ks * 32 + fq * 8);
      #pragma unroll
      for (int i = 0; i < 2; i++)
        #pragma unroll
        for (int j = 0; j < 2; j++)
          acc2[i][j] = __builtin_amdgcn_mfma_f32_16x16x32_bf16(vfr[i], pfr[j], acc2[i][j], 0, 0, 0);
    }
    float* obase = out + ((size_t)bb * D_ + dc * 64) * N_ + n0;
    #pragma unroll
    for (int i = 0; i < 2; i++)
      #pragma unroll
      for (int j = 0; j < 2; j++) {
        int mm = wm2 + j * 16 + fl;
        #pragma unroll
        for (int r = 0; r < 4; r++) {
          int d = wd + i * 16 + fq * 4 + r;
          obase[(size_t)d * N_ + mm] = acc2[i][j][r];
        }
      }
  }
}

extern "C" void kernel_launch(void* const* d_in, const int* in_sizes, int n_in,
                              void* d_out, int out_size, void* d_ws, size_t ws_size,
                              hipStream_t stream) {
  const float* vis  = (const float*)d_in[0];
  const float* text = (const float*)d_in[1];
  const float* Wq   = (const float*)d_in[2];
  const float* bq   = (const float*)d_in[3];
  const float* Wk   = (const float*)d_in[4];
  const float* bk   = (const float*)d_in[5];
  const float* Wv   = (const float*)d_in[6];
  const float* bv   = (const float*)d_in[7];
  float* out = (float*)d_out;
  char* ws = (char*)d_ws;

  unsigned short* textb = (unsigned short*)(ws + 0);
  unsigned short* Wkb   = (unsigned short*)(ws + 3145728);
  unsigned short* Wvb   = (unsigned short*)(ws + 4325376);
  unsigned short* WqTb  = (unsigned short*)(ws + 5505024);
  unsigned short* kb    = (unsigned short*)(ws + 6684672);
  unsigned short* kqb   = (unsigned short*)(ws + 9830400);
  unsigned short* vTb   = (unsigned short*)(ws + 12976128);
  float* ent_t = (float*)(ws + 16121856);
  float* ent_v = (float*)(ws + 16138240);
  float* skq   = (float*)(ws + 16662528);
  float* Sbuf  = (float*)(ws + 16777216);   // 33,554,432 B -> total ws 50,331,648 B

  // 1. weight casts + Wq transpose + text cast/entropy
  prep_kernel<<<dim3(24, 24, 4), 256, 0, stream>>>(Wk, Wv, Wq, text,
                                                   Wkb, Wvb, WqTb, textb, ent_t);
  // 2. k = text@Wk^T + bk || vT = (text@Wv^T + bv)^T
  gemm_kvT_kernel<<<dim3(32, 24), 256, 0, stream>>>(textb, Wkb, bk, kb, Wvb, bv, vTb);
  // 3. kq = k@Wq || skq = k@bq
  gemm_kq_bias_kernel<<<dim3(32, 28), 256, 0, stream>>>(kb, WqTb, kqb, bq, skq);
  // 4. S = vf*kq^T + inline visual entropy (vis read exactly once)
  attn_s_kernel<<<1024, 256, 0, stream>>>(vis, kqb, Sbuf, ent_v);
  // 5. block-local ve/te softmax + modulated softmax + PV -> out
  attn_pv_kernel<<<1024, 256, 0, stream>>>(Sbuf, vTb, ent_v, ent_t, skq, out);
}